// Round 1
// baseline (1332.798 us; speedup 1.0000x reference)
//
#include <hip/hip_runtime.h>

typedef unsigned short u16;
typedef __attribute__((ext_vector_type(8))) short bf16x8;
typedef __attribute__((ext_vector_type(4))) float f32x4;

#define MFMA16(a, b, c) __builtin_amdgcn_mfma_f32_16x16x32_bf16((a), (b), (c), 0, 0, 0)

__device__ __forceinline__ u16 f2bf(float f) {
  unsigned u = __float_as_uint(f);
  return (u16)((u + 0x7FFFu + ((u >> 16) & 1u)) >> 16);
}
__device__ __forceinline__ float bf2f(u16 h) { return __uint_as_float(((unsigned)h) << 16); }

// ---------------- elementwise split: fp32 -> bf16 hi + bf16 lo ----------------
__global__ void split_kernel(const float* __restrict__ in, u16* __restrict__ hi,
                             u16* __restrict__ lo, long n4) {
  long stride = (long)gridDim.x * blockDim.x;
  for (long i = (long)blockIdx.x * blockDim.x + threadIdx.x; i < n4; i += stride) {
    float4 v = ((const float4*)in)[i];
    ushort4 h, l;
    h.x = f2bf(v.x); l.x = f2bf(v.x - bf2f(h.x));
    h.y = f2bf(v.y); l.y = f2bf(v.y - bf2f(h.y));
    h.z = f2bf(v.z); l.z = f2bf(v.z - bf2f(h.z));
    h.w = f2bf(v.w); l.w = f2bf(v.w - bf2f(h.w));
    ((ushort4*)hi)[i] = h;
    ((ushort4*)lo)[i] = l;
  }
}

// ---------------- RoPE in place on q,k fp32 (B,H,N,hd) ----------------
__global__ void rope_kernel(float* __restrict__ q, float* __restrict__ k,
                            const int* __restrict__ pos, int B, int N) {
  const long total = (long)B * 16 * (N - 1) * 32;
  long stride = (long)gridDim.x * blockDim.x;
  for (long idx = (long)blockIdx.x * blockDim.x + threadIdx.x; idx < total; idx += stride) {
    int i = (int)(idx & 31);
    long r = idx >> 5;
    int tm1 = (int)(r % (N - 1));
    int bh = (int)(r / (N - 1));
    int b = bh >> 4;
    int p = pos[b * (N - 1) + tm1];
    // replicate reference fp32 rounding of freq and angle, then exact trig
    float fr = (float)pow(10000.0, -(double)i / 32.0);
    float angf = (float)p * fr;
    double sd, cd;
    sincos((double)angf, &sd, &cd);
    float s = (float)sd, c = (float)cd;
    size_t base = ((size_t)bh * N + (tm1 + 1)) * 64 + 2 * i;
    float re = q[base], im = q[base + 1];
    q[base]     = re * c - im * s;
    q[base + 1] = re * s + im * c;
    re = k[base]; im = k[base + 1];
    k[base]     = re * c - im * s;
    k[base + 1] = re * s + im * c;
  }
}

// ---------------- V: (B,H,N,hd) fp32 -> transposed split (B,H,hd,NP) bf16 hi/lo, zero-padded ----------------
__global__ __launch_bounds__(256) void vsplitT_kernel(const float* __restrict__ v,
                                                      u16* __restrict__ vth, u16* __restrict__ vtl,
                                                      int N, int NP) {
  __shared__ float tile[64][65];
  const int bh = blockIdx.y;
  const int t0 = blockIdx.x * 64;
  const float* vb = v + (size_t)bh * N * 64;
#pragma unroll
  for (int r = 0; r < 16; ++r) {
    int idx = r * 256 + threadIdx.x;
    int tl = idx >> 6, d = idx & 63;
    int t = t0 + tl;
    tile[tl][d] = (t < N) ? vb[(size_t)t * 64 + d] : 0.f;
  }
  __syncthreads();
  u16* oh = vth + (size_t)bh * 64 * NP;
  u16* ol = vtl + (size_t)bh * 64 * NP;
#pragma unroll
  for (int r = 0; r < 16; ++r) {
    int idx = r * 256 + threadIdx.x;
    int d = idx >> 6, tl = idx & 63;
    int t = t0 + tl;
    if (t < NP) {
      float val = tile[tl][d];
      u16 h = f2bf(val);
      oh[(size_t)d * NP + t] = h;
      ol[(size_t)d * NP + t] = f2bf(val - bf2f(h));
    }
  }
}

// ---------------- bf16x3 emulated-fp32 GEMM: C = A(MxK) * W(NxK)^T + bias ----------------
// EPI 0: scatter cols into q/k/v (B,H,N,hd) fp32.  EPI 1: row-major out.
__device__ __forceinline__ void stage_tile(const u16* __restrict__ g, u16* l,
                                           int row0, int rmax, int K, int k0, int tid) {
#pragma unroll
  for (int t = 0; t < 2; ++t) {
    int c = t * 256 + tid;
    int row = c >> 2, kc = (c & 3) << 3;
    int gr = row0 + row;
    if (gr > rmax) gr = rmax;
    const u16* gp = g + (size_t)gr * K + (k0 + kc);
    __builtin_amdgcn_global_load_lds((const __attribute__((address_space(1))) void*)gp,
                                     (__attribute__((address_space(3))) void*)(l + c * 8),
                                     16, 0, 0);
  }
}

template <int EPI>
__global__ __launch_bounds__(256) void gemm_bf16x3(
    const u16* __restrict__ Ah, const u16* __restrict__ Al,
    const u16* __restrict__ Bh, const u16* __restrict__ Bl,
    const float* __restrict__ bias,
    float* __restrict__ out0, float* __restrict__ out1, float* __restrict__ out2,
    int M, int Nn, int K, int Ntok) {
  __shared__ u16 lAh[4096], lAl[4096], lBh[4096], lBl[4096];
  const int tid = threadIdx.x;
  const int wid = tid >> 6, lane = tid & 63;
  const int wm = wid >> 1, wn = wid & 1;
  const int lg = lane >> 4, lm = lane & 15;
  const int mbase = blockIdx.y * 128, nbase = blockIdx.x * 128;

  f32x4 acc[4][4];
  const f32x4 zero = {0.f, 0.f, 0.f, 0.f};
#pragma unroll
  for (int a = 0; a < 4; ++a)
#pragma unroll
    for (int b = 0; b < 4; ++b) acc[a][b] = zero;

  for (int k0 = 0; k0 < K; k0 += 32) {
    stage_tile(Ah, lAh, mbase, M - 1, K, k0, tid);
    stage_tile(Al, lAl, mbase, M - 1, K, k0, tid);
    stage_tile(Bh, lBh, nbase, Nn - 1, K, k0, tid);
    stage_tile(Bl, lBl, nbase, Nn - 1, K, k0, tid);
    __syncthreads();
    bf16x8 afh[4], afl[4], bfh[4], bfl[4];
#pragma unroll
    for (int f = 0; f < 4; ++f) {
      afh[f] = *(const bf16x8*)&lAh[(wm * 64 + f * 16 + lm) * 32 + lg * 8];
      afl[f] = *(const bf16x8*)&lAl[(wm * 64 + f * 16 + lm) * 32 + lg * 8];
      bfh[f] = *(const bf16x8*)&lBh[(wn * 64 + f * 16 + lm) * 32 + lg * 8];
      bfl[f] = *(const bf16x8*)&lBl[(wn * 64 + f * 16 + lm) * 32 + lg * 8];
    }
#pragma unroll
    for (int fm = 0; fm < 4; ++fm)
#pragma unroll
      for (int fn = 0; fn < 4; ++fn) {
        acc[fm][fn] = MFMA16(afh[fm], bfh[fn], acc[fm][fn]);
        acc[fm][fn] = MFMA16(afh[fm], bfl[fn], acc[fm][fn]);
        acc[fm][fn] = MFMA16(afl[fm], bfh[fn], acc[fm][fn]);
      }
    __syncthreads();
  }

#pragma unroll
  for (int fm = 0; fm < 4; ++fm)
#pragma unroll
    for (int fn = 0; fn < 4; ++fn) {
      int col = nbase + wn * 64 + fn * 16 + lm;
      float bv = bias[col];
#pragma unroll
      for (int i = 0; i < 4; ++i) {
        int row = mbase + wm * 64 + fm * 16 + lg * 4 + i;
        if (row < M) {
          float v = acc[fm][fn][i] + bv;
          if (EPI == 1) {
            out0[(size_t)row * Nn + col] = v;
          } else {
            int which = col >> 10, h2 = (col >> 6) & 15, d2 = col & 63;
            int b2 = row / Ntok, t2 = row - b2 * Ntok;
            float* dst = (which == 0) ? out0 : (which == 1) ? out1 : out2;
            dst[(((size_t)(b2 * 16 + h2)) * Ntok + t2) * 64 + d2] = v;
          }
        }
      }
    }
}

// ---------------- flash attention, bf16x3 QK / split-P PV, fp32 softmax ----------------
__global__ __launch_bounds__(256) void attn_kernel(
    const u16* __restrict__ qh, const u16* __restrict__ ql,
    const u16* __restrict__ kh, const u16* __restrict__ kl,
    const u16* __restrict__ vth, const u16* __restrict__ vtl,
    float* __restrict__ out, int N, int NP) {
  __shared__ u16 Ph[4][16][32];
  __shared__ u16 Pl[4][16][32];
  const int bh = blockIdx.y;
  const int b = bh >> 4, h = bh & 15;
  const int tid = threadIdx.x;
  const int wid = tid >> 6, lane = tid & 63;
  const int lg = lane >> 4, lm = lane & 15;
  const int qbase = blockIdx.x * 64 + wid * 16;
  const size_t bhoff = (size_t)bh * N * 64;

  int qr = qbase + lm;
  if (qr > N - 1) qr = N - 1;
  const u16* qp_h = qh + bhoff + (size_t)qr * 64;
  const u16* qp_l = ql + bhoff + (size_t)qr * 64;
  bf16x8 qfh[2], qfl[2];
  qfh[0] = *(const bf16x8*)(qp_h + lg * 8);
  qfh[1] = *(const bf16x8*)(qp_h + 32 + lg * 8);
  qfl[0] = *(const bf16x8*)(qp_l + lg * 8);
  qfl[1] = *(const bf16x8*)(qp_l + 32 + lg * 8);

  const f32x4 zero = {0.f, 0.f, 0.f, 0.f};
  f32x4 oacc[4];
#pragma unroll
  for (int c = 0; c < 4; ++c) oacc[c] = zero;
  float m_i[4], l_i[4];
#pragma unroll
  for (int i = 0; i < 4; ++i) { m_i[i] = -1e30f; l_i[i] = 0.f; }
  const float scale = 0.125f;

  for (int kv0 = 0; kv0 < N; kv0 += 32) {
    f32x4 s[2];
    s[0] = zero; s[1] = zero;
#pragma unroll
    for (int cf = 0; cf < 2; ++cf) {
      int key = kv0 + cf * 16 + lm;
      if (key > N - 1) key = N - 1;
      const u16* kp_h = kh + bhoff + (size_t)key * 64 + lg * 8;
      const u16* kp_l = kl + bhoff + (size_t)key * 64 + lg * 8;
#pragma unroll
      for (int dk = 0; dk < 2; ++dk) {
        bf16x8 kbh = *(const bf16x8*)(kp_h + dk * 32);
        bf16x8 kbl = *(const bf16x8*)(kp_l + dk * 32);
        s[cf] = MFMA16(qfh[dk], kbh, s[cf]);
        s[cf] = MFMA16(qfh[dk], kbl, s[cf]);
        s[cf] = MFMA16(qfl[dk], kbh, s[cf]);
      }
    }
    // scale + mask + row stats (rows replicated across the 16-lane group)
    float rmax[4];
    bool mask0 = (kv0 + lm >= N), mask1 = (kv0 + 16 + lm >= N);
#pragma unroll
    for (int i = 0; i < 4; ++i) {
      float s0 = mask0 ? -1e30f : s[0][i] * scale;
      float s1 = mask1 ? -1e30f : s[1][i] * scale;
      s[0][i] = s0; s[1][i] = s1;
      rmax[i] = fmaxf(s0, s1);
    }
#pragma unroll
    for (int off = 8; off >= 1; off >>= 1)
#pragma unroll
      for (int i = 0; i < 4; ++i) rmax[i] = fmaxf(rmax[i], __shfl_xor(rmax[i], off));
    float sc[4], psum[4];
#pragma unroll
    for (int i = 0; i < 4; ++i) {
      float mnew = fmaxf(m_i[i], rmax[i]);
      sc[i] = __expf(m_i[i] - mnew);
      float p0 = __expf(s[0][i] - mnew);
      float p1 = __expf(s[1][i] - mnew);
      psum[i] = p0 + p1;
      u16 h0 = f2bf(p0), h1 = f2bf(p1);
      Ph[wid][lg * 4 + i][lm] = h0;
      Ph[wid][lg * 4 + i][16 + lm] = h1;
      Pl[wid][lg * 4 + i][lm] = f2bf(p0 - bf2f(h0));
      Pl[wid][lg * 4 + i][16 + lm] = f2bf(p1 - bf2f(h1));
      m_i[i] = mnew;
    }
#pragma unroll
    for (int off = 8; off >= 1; off >>= 1)
#pragma unroll
      for (int i = 0; i < 4; ++i) psum[i] += __shfl_xor(psum[i], off);
#pragma unroll
    for (int i = 0; i < 4; ++i) l_i[i] = l_i[i] * sc[i] + psum[i];
#pragma unroll
    for (int cf = 0; cf < 4; ++cf)
#pragma unroll
      for (int i = 0; i < 4; ++i) oacc[cf][i] *= sc[i];

    __syncthreads();  // order P writes (D-layout) before A-layout reads
    bf16x8 pah = *(const bf16x8*)&Ph[wid][lm][lg * 8];
    bf16x8 pal = *(const bf16x8*)&Pl[wid][lm][lg * 8];
    const u16* vp_h = vth + (size_t)bh * 64 * NP + kv0 + lg * 8;
    const u16* vp_l = vtl + (size_t)bh * 64 * NP + kv0 + lg * 8;
#pragma unroll
    for (int cf = 0; cf < 4; ++cf) {
      int d = cf * 16 + lm;
      bf16x8 vbh = *(const bf16x8*)(vp_h + (size_t)d * NP);
      bf16x8 vbl = *(const bf16x8*)(vp_l + (size_t)d * NP);
      oacc[cf] = MFMA16(pah, vbh, oacc[cf]);
      oacc[cf] = MFMA16(pah, vbl, oacc[cf]);
      oacc[cf] = MFMA16(pal, vbh, oacc[cf]);
    }
  }

#pragma unroll
  for (int cf = 0; cf < 4; ++cf)
#pragma unroll
    for (int i = 0; i < 4; ++i) {
      int t = qbase + lg * 4 + i;
      if (t < N)
        out[((size_t)b * N + t) * 1024 + h * 64 + cf * 16 + lm] = oacc[cf][i] / l_i[i];
    }
}

// ---------------- orchestration ----------------
extern "C" void kernel_launch(void* const* d_in, const int* in_sizes, int n_in,
                              void* d_out, int out_size, void* d_ws, size_t ws_size,
                              hipStream_t stream) {
  const float* x     = (const float*)d_in[0];
  const int*   pos   = (const int*)  d_in[1];
  const float* w_qkv = (const float*)d_in[2];
  const float* b_qkv = (const float*)d_in[3];
  const float* w_fc  = (const float*)d_in[4];
  const float* b_fc  = (const float*)d_in[5];
  (void)in_sizes; (void)n_in; (void)out_size; (void)ws_size;

  const int B = 4, N = 2049, NP = 2080;
  const long EL = (long)B * N * 1024;  // 8,392,704

  char* base = (char*)d_ws;
  size_t off = 0;
  auto alloc = [&](size_t bytes) -> void* {
    void* p = base + off;
    off += (bytes + 255) & ~(size_t)255;
    return p;
  };
  float* qf = (float*)alloc(EL * 4);
  float* kf = (float*)alloc(EL * 4);
  float* vf = (float*)alloc(EL * 4);
  u16* qhh = (u16*)alloc(EL * 2);
  u16* qll = (u16*)alloc(EL * 2);
  u16* khh = (u16*)alloc(EL * 2);
  u16* kll = (u16*)alloc(EL * 2);
  u16* vth = (u16*)alloc((size_t)64 * 64 * NP * 2);
  u16* vtl = (u16*)alloc((size_t)64 * 64 * NP * 2);
  u16* xh  = (u16*)alloc(EL * 2);
  u16* xl  = (u16*)alloc(EL * 2);
  u16* wqh = (u16*)alloc((size_t)3072 * 1024 * 2);
  u16* wql = (u16*)alloc((size_t)3072 * 1024 * 2);
  u16* wfh = (u16*)alloc((size_t)1024 * 1024 * 2);
  u16* wfl = (u16*)alloc((size_t)1024 * 1024 * 2);

  // 1. split inputs to bf16 hi/lo
  split_kernel<<<2048, 256, 0, stream>>>(x, xh, xl, EL / 4);
  split_kernel<<<1024, 256, 0, stream>>>(w_qkv, wqh, wql, (long)3072 * 1024 / 4);
  split_kernel<<<512, 256, 0, stream>>>(w_fc, wfh, wfl, (long)1024 * 1024 / 4);
  // 2. fused QKV projection -> q,k,v fp32 in (B,H,N,hd)
  gemm_bf16x3<0><<<dim3(24, 65), 256, 0, stream>>>(xh, xl, wqh, wql, b_qkv,
                                                   qf, kf, vf, 8196, 3072, 1024, N);
  // 3. RoPE in place on q,k (skips cls token t=0)
  rope_kernel<<<2048, 256, 0, stream>>>(qf, kf, pos, B, N);
  // 4. split q,k; transpose+split+pad v
  split_kernel<<<2048, 256, 0, stream>>>(qf, qhh, qll, EL / 4);
  split_kernel<<<2048, 256, 0, stream>>>(kf, khh, kll, EL / 4);
  vsplitT_kernel<<<dim3((NP + 63) / 64, 64), 256, 0, stream>>>(vf, vth, vtl, N, NP);
  // 5. flash attention -> (B,N,D) fp32 (reuses qf region)
  attn_kernel<<<dim3(33, 64), 256, 0, stream>>>(qhh, qll, khh, kll, vth, vtl, qf, N, NP);
  // 6. split attention output (reuses xh/xl), output projection -> d_out
  split_kernel<<<2048, 256, 0, stream>>>(qf, xh, xl, EL / 4);
  gemm_bf16x3<1><<<dim3(8, 65), 256, 0, stream>>>(xh, xl, wfh, wfl, b_fc,
                                                  (float*)d_out, nullptr, nullptr,
                                                  8196, 1024, 1024, N);
}

// Round 2
// 1134.002 us; speedup vs baseline: 1.1753x; 1.1753x over previous
//
#include <hip/hip_runtime.h>

typedef unsigned short u16;
typedef __attribute__((ext_vector_type(8))) short bf16x8;
typedef __attribute__((ext_vector_type(4))) float f32x4;

#define MFMA16(a, b, c) __builtin_amdgcn_mfma_f32_16x16x32_bf16((a), (b), (c), 0, 0, 0)

__device__ __forceinline__ u16 f2bf(float f) {
  unsigned u = __float_as_uint(f);
  return (u16)((u + 0x7FFFu + ((u >> 16) & 1u)) >> 16);
}
__device__ __forceinline__ float bf2f(u16 h) { return __uint_as_float(((unsigned)h) << 16); }
// packed f32x2 -> bf16x2 (RNE), lo word = a, hi word = b
__device__ __forceinline__ unsigned cvt_pk(float a, float b) {
  unsigned r;
  asm("v_cvt_pk_bf16_f32 %0, %1, %2" : "=v"(r) : "v"(a), "v"(b));
  return r;
}

// ---------------- elementwise split: fp32 -> bf16 hi + bf16 lo ----------------
__global__ void split_kernel(const float* __restrict__ in, u16* __restrict__ hi,
                             u16* __restrict__ lo, long n4) {
  long stride = (long)gridDim.x * blockDim.x;
  for (long i = (long)blockIdx.x * blockDim.x + threadIdx.x; i < n4; i += stride) {
    float4 v = ((const float4*)in)[i];
    ushort4 h, l;
    h.x = f2bf(v.x); l.x = f2bf(v.x - bf2f(h.x));
    h.y = f2bf(v.y); l.y = f2bf(v.y - bf2f(h.y));
    h.z = f2bf(v.z); l.z = f2bf(v.z - bf2f(h.z));
    h.w = f2bf(v.w); l.w = f2bf(v.w - bf2f(h.w));
    ((ushort4*)hi)[i] = h;
    ((ushort4*)lo)[i] = l;
  }
}

// ---------------- RoPE fused with split: q,k fp32 (B,H,N,hd) -> bf16 hi/lo ----------------
__global__ void rope_split_kernel(const float* __restrict__ qf, const float* __restrict__ kf,
                                  const int* __restrict__ pos,
                                  u16* __restrict__ qh, u16* __restrict__ ql,
                                  u16* __restrict__ kh, u16* __restrict__ kl,
                                  int B, int N) {
  const long total = (long)B * 16 * N * 32;
  long stride = (long)gridDim.x * blockDim.x;
  for (long idx = (long)blockIdx.x * blockDim.x + threadIdx.x; idx < total; idx += stride) {
    int i = (int)(idx & 31);
    long r = idx >> 5;
    int t = (int)(r % N);
    int bh = (int)(r / N);
    int b = bh >> 4;
    float c = 1.f, s = 0.f;
    if (t > 0) {
      int p = pos[b * (N - 1) + (t - 1)];
      // replicate reference fp32 rounding of freq and angle, then exact trig
      float fr = (float)pow(10000.0, -(double)i / 32.0);
      float angf = (float)p * fr;
      double sd, cd;
      sincos((double)angf, &sd, &cd);
      s = (float)sd; c = (float)cd;
    }
    size_t base = ((size_t)bh * N + t) * 64 + 2 * i;
    float2 qv = *(const float2*)(qf + base);
    float2 kv = *(const float2*)(kf + base);
    float qre = qv.x * c - qv.y * s, qim = qv.x * s + qv.y * c;
    float kre = kv.x * c - kv.y * s, kim = kv.x * s + kv.y * c;
    unsigned qhp = cvt_pk(qre, qim);
    unsigned qlp = cvt_pk(qre - __uint_as_float(qhp << 16),
                          qim - __uint_as_float(qhp & 0xffff0000u));
    unsigned khp = cvt_pk(kre, kim);
    unsigned klp = cvt_pk(kre - __uint_as_float(khp << 16),
                          kim - __uint_as_float(khp & 0xffff0000u));
    *(unsigned*)(qh + base) = qhp;
    *(unsigned*)(ql + base) = qlp;
    *(unsigned*)(kh + base) = khp;
    *(unsigned*)(kl + base) = klp;
  }
}

// ---------------- V: (B,H,N,hd) fp32 -> transposed split (B,H,hd,NP) bf16 hi/lo, zero-padded ----------------
__global__ __launch_bounds__(256) void vsplitT_kernel(const float* __restrict__ v,
                                                      u16* __restrict__ vth, u16* __restrict__ vtl,
                                                      int N, int NP) {
  __shared__ float tile[64][65];
  const int bh = blockIdx.y;
  const int t0 = blockIdx.x * 64;
  const float* vb = v + (size_t)bh * N * 64;
#pragma unroll
  for (int r = 0; r < 16; ++r) {
    int idx = r * 256 + threadIdx.x;
    int tl = idx >> 6, d = idx & 63;
    int t = t0 + tl;
    tile[tl][d] = (t < N) ? vb[(size_t)t * 64 + d] : 0.f;
  }
  __syncthreads();
  u16* oh = vth + (size_t)bh * 64 * NP;
  u16* ol = vtl + (size_t)bh * 64 * NP;
#pragma unroll
  for (int r = 0; r < 16; ++r) {
    int idx = r * 256 + threadIdx.x;
    int d = idx >> 6, tl = idx & 63;
    int t = t0 + tl;
    if (t < NP) {
      float val = tile[tl][d];
      u16 h = f2bf(val);
      oh[(size_t)d * NP + t] = h;
      ol[(size_t)d * NP + t] = f2bf(val - bf2f(h));
    }
  }
}

// ---------------- bf16x3 emulated-fp32 GEMM: C = A(MxK) * W(NxK)^T + bias ----------------
// EPI 0: scatter cols into q/k/v (B,H,N,hd) fp32, q pre-scaled by 0.125*log2(e).
// EPI 1: row-major out.
__device__ __forceinline__ void stage_tile(const u16* __restrict__ g, u16* l,
                                           int row0, int rmax, int K, int k0, int tid) {
#pragma unroll
  for (int t = 0; t < 2; ++t) {
    int c = t * 256 + tid;
    int row = c >> 2, kc = (c & 3) << 3;
    int gr = row0 + row;
    if (gr > rmax) gr = rmax;
    const u16* gp = g + (size_t)gr * K + (k0 + kc);
    __builtin_amdgcn_global_load_lds((const __attribute__((address_space(1))) void*)gp,
                                     (__attribute__((address_space(3))) void*)(l + c * 8),
                                     16, 0, 0);
  }
}

template <int EPI>
__global__ __launch_bounds__(256) void gemm_bf16x3(
    const u16* __restrict__ Ah, const u16* __restrict__ Al,
    const u16* __restrict__ Bh, const u16* __restrict__ Bl,
    const float* __restrict__ bias,
    float* __restrict__ out0, float* __restrict__ out1, float* __restrict__ out2,
    int M, int Nn, int K, int Ntok) {
  __shared__ u16 lAh[4096], lAl[4096], lBh[4096], lBl[4096];
  const int tid = threadIdx.x;
  const int wid = tid >> 6, lane = tid & 63;
  const int wm = wid >> 1, wn = wid & 1;
  const int lg = lane >> 4, lm = lane & 15;
  const int mbase = blockIdx.y * 128, nbase = blockIdx.x * 128;

  f32x4 acc[4][4];
  const f32x4 zero = {0.f, 0.f, 0.f, 0.f};
#pragma unroll
  for (int a = 0; a < 4; ++a)
#pragma unroll
    for (int b = 0; b < 4; ++b) acc[a][b] = zero;

  for (int k0 = 0; k0 < K; k0 += 32) {
    stage_tile(Ah, lAh, mbase, M - 1, K, k0, tid);
    stage_tile(Al, lAl, mbase, M - 1, K, k0, tid);
    stage_tile(Bh, lBh, nbase, Nn - 1, K, k0, tid);
    stage_tile(Bl, lBl, nbase, Nn - 1, K, k0, tid);
    __syncthreads();
    bf16x8 afh[4], afl[4], bfh[4], bfl[4];
#pragma unroll
    for (int f = 0; f < 4; ++f) {
      afh[f] = *(const bf16x8*)&lAh[(wm * 64 + f * 16 + lm) * 32 + lg * 8];
      afl[f] = *(const bf16x8*)&lAl[(wm * 64 + f * 16 + lm) * 32 + lg * 8];
      bfh[f] = *(const bf16x8*)&lBh[(wn * 64 + f * 16 + lm) * 32 + lg * 8];
      bfl[f] = *(const bf16x8*)&lBl[(wn * 64 + f * 16 + lm) * 32 + lg * 8];
    }
#pragma unroll
    for (int fm = 0; fm < 4; ++fm)
#pragma unroll
      for (int fn = 0; fn < 4; ++fn) {
        acc[fm][fn] = MFMA16(afh[fm], bfh[fn], acc[fm][fn]);
        acc[fm][fn] = MFMA16(afh[fm], bfl[fn], acc[fm][fn]);
        acc[fm][fn] = MFMA16(afl[fm], bfh[fn], acc[fm][fn]);
      }
    __syncthreads();
  }

#pragma unroll
  for (int fm = 0; fm < 4; ++fm)
#pragma unroll
    for (int fn = 0; fn < 4; ++fn) {
      int col = nbase + wn * 64 + fn * 16 + lm;
      float bv = bias[col];
#pragma unroll
      for (int i = 0; i < 4; ++i) {
        int row = mbase + wm * 64 + fm * 16 + lg * 4 + i;
        if (row < M) {
          float v = acc[fm][fn][i] + bv;
          if (EPI == 1) {
            out0[(size_t)row * Nn + col] = v;
          } else {
            // fold softmax scale (1/8) and exp->exp2 conversion into q
            if (col < 1024) v *= 0.18033688011112042f;  // 0.125 * log2(e)
            int which = col >> 10, h2 = (col >> 6) & 15, d2 = col & 63;
            int b2 = row / Ntok, t2 = row - b2 * Ntok;
            float* dst = (which == 0) ? out0 : (which == 1) ? out1 : out2;
            dst[(((size_t)(b2 * 16 + h2)) * Ntok + t2) * 64 + d2] = v;
          }
        }
      }
    }
}

// ---------------- flash attention: swapped QK^T, in-register exp2 softmax, no barriers ----------------
// S^T = mfma(A=K, B=Q): lane holds q-row (lane&15), keys (lane>>4)*4+i per fragment.
// O^T = mfma(A=V^T, B=P^T): P redistributed lane-local via wave-private LDS exchange.
__global__ __launch_bounds__(256) void attn_kernel(
    const u16* __restrict__ qh, const u16* __restrict__ ql,
    const u16* __restrict__ kh, const u16* __restrict__ kl,
    const u16* __restrict__ vth, const u16* __restrict__ vtl,
    u16* __restrict__ outh, u16* __restrict__ outl, int N, int NP) {
  __shared__ unsigned pex[4][64][4];  // per-wave P exchange, no cross-wave use
  const int id = blockIdx.x;
  const int swz = (id & 7) * 264 + (id >> 3);  // XCD-bijective swizzle (2112 = 8*264)
  const int qblk = swz % 33;
  const int bh = swz / 33;
  const int b = bh >> 4, h = bh & 15;
  const int tid = threadIdx.x;
  const int wid = tid >> 6, lane = tid & 63;
  const int lg = lane >> 4, lm = lane & 15;
  const int qbase = qblk * 64 + wid * 16;
  const size_t bhoff = (size_t)bh * N * 64;
  const size_t voff = (size_t)bh * 64 * NP;

  // Q B-frag: col=lm -> q-row, k=lg*8+j -> d
  int qr = qbase + lm;
  if (qr > N - 1) qr = N - 1;
  const u16* qp_h = qh + bhoff + (size_t)qr * 64 + lg * 8;
  const u16* qp_l = ql + bhoff + (size_t)qr * 64 + lg * 8;
  bf16x8 qfh[2], qfl[2];
  qfh[0] = *(const bf16x8*)(qp_h);
  qfh[1] = *(const bf16x8*)(qp_h + 32);
  qfl[0] = *(const bf16x8*)(qp_l);
  qfl[1] = *(const bf16x8*)(qp_l + 32);

  const f32x4 zero = {0.f, 0.f, 0.f, 0.f};
  f32x4 oacc[4];
#pragma unroll
  for (int c = 0; c < 4; ++c) oacc[c] = zero;
  float m = -1e30f, l = 0.f;

  // K A-frag base: row=lm -> key-in-16, k=lg*8+j -> d
  const u16* kp_h = kh + bhoff + (size_t)lm * 64 + lg * 8;
  const u16* kp_l = kl + bhoff + (size_t)lm * 64 + lg * 8;
  // V^T A-frag base: row=lm -> d-in-16, k=lg*8+j -> key
  const u16* vp_h = vth + voff + (size_t)lm * NP + lg * 8;
  const u16* vp_l = vtl + voff + (size_t)lm * NP + lg * 8;

  const int cfs2 = (lg >> 1) * 2;          // u-word offset to read
  const int ga = (lg & 1) * 2, gb = ga + 1;  // source lg groups

  for (int kv0 = 0; kv0 < N; kv0 += 32) {
    f32x4 s[2];
    s[0] = zero; s[1] = zero;
    if (kv0 + 32 <= N) {  // fast path: no masking, no clamping
      const u16* kb_h = kp_h + (size_t)kv0 * 64;
      const u16* kb_l = kp_l + (size_t)kv0 * 64;
#pragma unroll
      for (int cf = 0; cf < 2; ++cf)
#pragma unroll
        for (int dk = 0; dk < 2; ++dk) {
          bf16x8 k_h = *(const bf16x8*)(kb_h + cf * 1024 + dk * 32);
          bf16x8 k_l = *(const bf16x8*)(kb_l + cf * 1024 + dk * 32);
          s[cf] = MFMA16(k_h, qfh[dk], s[cf]);
          s[cf] = MFMA16(k_l, qfh[dk], s[cf]);
          s[cf] = MFMA16(k_h, qfl[dk], s[cf]);
        }
    } else {  // tail tile: clamp rows, mask scores
#pragma unroll
      for (int cf = 0; cf < 2; ++cf) {
        int key = kv0 + cf * 16 + lm;
        if (key > N - 1) key = N - 1;
        const u16* kb_h = kh + bhoff + (size_t)key * 64 + lg * 8;
        const u16* kb_l = kl + bhoff + (size_t)key * 64 + lg * 8;
#pragma unroll
        for (int dk = 0; dk < 2; ++dk) {
          bf16x8 k_h = *(const bf16x8*)(kb_h + dk * 32);
          bf16x8 k_l = *(const bf16x8*)(kb_l + dk * 32);
          s[cf] = MFMA16(k_h, qfh[dk], s[cf]);
          s[cf] = MFMA16(k_l, qfh[dk], s[cf]);
          s[cf] = MFMA16(k_h, qfl[dk], s[cf]);
        }
      }
#pragma unroll
      for (int cf = 0; cf < 2; ++cf)
#pragma unroll
        for (int i = 0; i < 4; ++i)
          if (kv0 + cf * 16 + lg * 4 + i >= N) s[cf][i] = -1e30f;
    }

    // in-register softmax (exp2 domain; scale folded into q)
    float mx = fmaxf(fmaxf(fmaxf(s[0][0], s[0][1]), fmaxf(s[0][2], s[0][3])),
                     fmaxf(fmaxf(s[1][0], s[1][1]), fmaxf(s[1][2], s[1][3])));
    mx = fmaxf(mx, __shfl_xor(mx, 16));
    mx = fmaxf(mx, __shfl_xor(mx, 32));
    float mnew = fmaxf(m, mx);
    float sc = __builtin_amdgcn_exp2f(m - mnew);
    float p[8];
#pragma unroll
    for (int cf = 0; cf < 2; ++cf)
#pragma unroll
      for (int i = 0; i < 4; ++i)
        p[cf * 4 + i] = __builtin_amdgcn_exp2f(s[cf][i] - mnew);
    float ps = ((p[0] + p[1]) + (p[2] + p[3])) + ((p[4] + p[5]) + (p[6] + p[7]));
    ps += __shfl_xor(ps, 16);
    ps += __shfl_xor(ps, 32);
    l = l * sc + ps;
    m = mnew;

    // pack P (hi only) and redistribute to B-frag layout via wave-private LDS
    uint4 uw;
    uw.x = cvt_pk(p[0], p[1]);
    uw.y = cvt_pk(p[2], p[3]);
    uw.z = cvt_pk(p[4], p[5]);
    uw.w = cvt_pk(p[6], p[7]);
    *(uint4*)&pex[wid][lg * 16 + lm][0] = uw;
    uint2 r0 = *(const uint2*)&pex[wid][ga * 16 + lm][cfs2];
    uint2 r1 = *(const uint2*)&pex[wid][gb * 16 + lm][cfs2];
    uint4 pu = make_uint4(r0.x, r0.y, r1.x, r1.y);
    bf16x8 pb = __builtin_bit_cast(bf16x8, pu);

    // rescale O and accumulate PV
#pragma unroll
    for (int c = 0; c < 4; ++c)
#pragma unroll
      for (int i = 0; i < 4; ++i) oacc[c][i] *= sc;
    const u16* vb_h = vp_h + kv0;
    const u16* vb_l = vp_l + kv0;
#pragma unroll
    for (int c = 0; c < 4; ++c) {
      bf16x8 v_h = *(const bf16x8*)(vb_h + (size_t)c * 16 * NP);
      bf16x8 v_l = *(const bf16x8*)(vb_l + (size_t)c * 16 * NP);
      oacc[c] = MFMA16(v_h, pb, oacc[c]);
      oacc[c] = MFMA16(v_l, pb, oacc[c]);
    }
  }

  // epilogue: O/l -> bf16 hi/lo directly (feeds final GEMM)
  int t = qbase + lm;
  if (t < N) {
    float rl = 1.f / l;
    size_t rowoff = ((size_t)(b * N + t)) * 1024 + h * 64 + lg * 4;
#pragma unroll
    for (int c = 0; c < 4; ++c) {
      float v0 = oacc[c][0] * rl, v1 = oacc[c][1] * rl;
      float v2 = oacc[c][2] * rl, v3 = oacc[c][3] * rl;
      unsigned h01 = cvt_pk(v0, v1), h23 = cvt_pk(v2, v3);
      unsigned l01 = cvt_pk(v0 - __uint_as_float(h01 << 16),
                            v1 - __uint_as_float(h01 & 0xffff0000u));
      unsigned l23 = cvt_pk(v2 - __uint_as_float(h23 << 16),
                            v3 - __uint_as_float(h23 & 0xffff0000u));
      *(uint2*)(outh + rowoff + c * 16) = make_uint2(h01, h23);
      *(uint2*)(outl + rowoff + c * 16) = make_uint2(l01, l23);
    }
  }
}

// ---------------- orchestration ----------------
extern "C" void kernel_launch(void* const* d_in, const int* in_sizes, int n_in,
                              void* d_out, int out_size, void* d_ws, size_t ws_size,
                              hipStream_t stream) {
  const float* x     = (const float*)d_in[0];
  const int*   pos   = (const int*)  d_in[1];
  const float* w_qkv = (const float*)d_in[2];
  const float* b_qkv = (const float*)d_in[3];
  const float* w_fc  = (const float*)d_in[4];
  const float* b_fc  = (const float*)d_in[5];
  (void)in_sizes; (void)n_in; (void)out_size; (void)ws_size;

  const int B = 4, N = 2049, NP = 2080;
  const long EL = (long)B * N * 1024;  // 8,392,704

  char* base = (char*)d_ws;
  size_t off = 0;
  auto alloc = [&](size_t bytes) -> void* {
    void* p = base + off;
    off += (bytes + 255) & ~(size_t)255;
    return p;
  };
  float* qf = (float*)alloc(EL * 4);
  float* kf = (float*)alloc(EL * 4);
  float* vf = (float*)alloc(EL * 4);
  u16* qhh = (u16*)alloc(EL * 2);
  u16* qll = (u16*)alloc(EL * 2);
  u16* khh = (u16*)alloc(EL * 2);
  u16* kll = (u16*)alloc(EL * 2);
  u16* vth = (u16*)alloc((size_t)64 * 64 * NP * 2);
  u16* vtl = (u16*)alloc((size_t)64 * 64 * NP * 2);
  u16* xh  = (u16*)alloc(EL * 2);
  u16* xl  = (u16*)alloc(EL * 2);
  u16* wqh = (u16*)alloc((size_t)3072 * 1024 * 2);
  u16* wql = (u16*)alloc((size_t)3072 * 1024 * 2);
  u16* wfh = (u16*)alloc((size_t)1024 * 1024 * 2);
  u16* wfl = (u16*)alloc((size_t)1024 * 1024 * 2);

  // 1. split inputs to bf16 hi/lo
  split_kernel<<<2048, 256, 0, stream>>>(x, xh, xl, EL / 4);
  split_kernel<<<1024, 256, 0, stream>>>(w_qkv, wqh, wql, (long)3072 * 1024 / 4);
  split_kernel<<<512, 256, 0, stream>>>(w_fc, wfh, wfl, (long)1024 * 1024 / 4);
  // 2. fused QKV projection -> q,k,v fp32 in (B,H,N,hd); q pre-scaled for exp2 softmax
  gemm_bf16x3<0><<<dim3(24, 65), 256, 0, stream>>>(xh, xl, wqh, wql, b_qkv,
                                                   qf, kf, vf, 8196, 3072, 1024, N);
  // 3. RoPE + split q,k (covers cls token as identity)
  rope_split_kernel<<<2048, 256, 0, stream>>>(qf, kf, pos, qhh, qll, khh, kll, B, N);
  // 4. transpose+split+pad v
  vsplitT_kernel<<<dim3((NP + 63) / 64, 64), 256, 0, stream>>>(vf, vth, vtl, N, NP);
  // 5. flash attention -> bf16 hi/lo (B,N,D), reusing xh/xl (input-x split already consumed)
  attn_kernel<<<dim3(2112), 256, 0, stream>>>(qhh, qll, khh, kll, vth, vtl, xh, xl, N, NP);
  // 6. output projection -> d_out
  gemm_bf16x3<1><<<dim3(8, 65), 256, 0, stream>>>(xh, xl, wfh, wfl, b_fc,
                                                  (float*)d_out, nullptr, nullptr,
                                                  8196, 1024, 1024, N);
}

// Round 3
// 699.151 us; speedup vs baseline: 1.9063x; 1.6220x over previous
//
#include <hip/hip_runtime.h>

typedef unsigned short u16;
typedef __attribute__((ext_vector_type(8))) short bf16x8;
typedef __attribute__((ext_vector_type(4))) float f32x4;

#define MFMA16(a, b, c) __builtin_amdgcn_mfma_f32_16x16x32_bf16((a), (b), (c), 0, 0, 0)

__device__ __forceinline__ u16 f2bf(float f) {
  unsigned u = __float_as_uint(f);
  return (u16)((u + 0x7FFFu + ((u >> 16) & 1u)) >> 16);
}
__device__ __forceinline__ float bf2f(u16 h) { return __uint_as_float(((unsigned)h) << 16); }
// packed f32x2 -> bf16x2 (RNE), lo word = a, hi word = b
__device__ __forceinline__ unsigned cvt_pk(float a, float b) {
  unsigned r;
  asm("v_cvt_pk_bf16_f32 %0, %1, %2" : "=v"(r) : "v"(a), "v"(b));
  return r;
}

// ---------------- elementwise split: fp32 -> bf16 hi + bf16 lo ----------------
__global__ void split_kernel(const float* __restrict__ in, u16* __restrict__ hi,
                             u16* __restrict__ lo, long n4) {
  long stride = (long)gridDim.x * blockDim.x;
  for (long i = (long)blockIdx.x * blockDim.x + threadIdx.x; i < n4; i += stride) {
    float4 v = ((const float4*)in)[i];
    ushort4 h, l;
    h.x = f2bf(v.x); l.x = f2bf(v.x - bf2f(h.x));
    h.y = f2bf(v.y); l.y = f2bf(v.y - bf2f(h.y));
    h.z = f2bf(v.z); l.z = f2bf(v.z - bf2f(h.z));
    h.w = f2bf(v.w); l.w = f2bf(v.w - bf2f(h.w));
    ((ushort4*)hi)[i] = h;
    ((ushort4*)lo)[i] = l;
  }
}

// ---------------- RoPE fused with split: q (N tokens), k (padded to NP tokens) ----------------
__global__ void rope_split_kernel(const float* __restrict__ qf, const float* __restrict__ kf,
                                  const int* __restrict__ pos,
                                  u16* __restrict__ qh, u16* __restrict__ ql,
                                  u16* __restrict__ kh, u16* __restrict__ kl,
                                  int B, int N, int NP) {
  const long total = (long)B * 16 * NP * 32;
  long stride = (long)gridDim.x * blockDim.x;
  for (long idx = (long)blockIdx.x * blockDim.x + threadIdx.x; idx < total; idx += stride) {
    int i = (int)(idx & 31);
    long r = idx >> 5;
    int t = (int)(r % NP);
    int bh = (int)(r / NP);
    int b = bh >> 4;
    size_t kb = ((size_t)bh * NP + t) * 64 + 2 * i;
    if (t >= N) {  // zero-pad K region (V handled in vsplitT)
      *(unsigned*)(kh + kb) = 0;
      *(unsigned*)(kl + kb) = 0;
      continue;
    }
    float c = 1.f, s = 0.f;
    if (t > 0) {
      int p = pos[b * (N - 1) + (t - 1)];
      // replicate reference fp32 rounding of freq and angle, then exact trig
      float fr = (float)pow(10000.0, -(double)i / 32.0);
      float angf = (float)p * fr;
      double sd, cd;
      sincos((double)angf, &sd, &cd);
      s = (float)sd; c = (float)cd;
    }
    size_t qb = ((size_t)bh * N + t) * 64 + 2 * i;
    float2 qv = *(const float2*)(qf + qb);
    float2 kv = *(const float2*)(kf + qb);
    float qre = qv.x * c - qv.y * s, qim = qv.x * s + qv.y * c;
    float kre = kv.x * c - kv.y * s, kim = kv.x * s + kv.y * c;
    unsigned qhp = cvt_pk(qre, qim);
    unsigned qlp = cvt_pk(qre - __uint_as_float(qhp << 16),
                          qim - __uint_as_float(qhp & 0xffff0000u));
    unsigned khp = cvt_pk(kre, kim);
    unsigned klp = cvt_pk(kre - __uint_as_float(khp << 16),
                          kim - __uint_as_float(khp & 0xffff0000u));
    *(unsigned*)(qh + qb) = qhp;
    *(unsigned*)(ql + qb) = qlp;
    *(unsigned*)(kh + kb) = khp;
    *(unsigned*)(kl + kb) = klp;
  }
}

// ---------------- V: (B,H,N,hd) fp32 -> transposed split (B,H,hd,NP) bf16 hi/lo, zero-padded ----------------
__global__ __launch_bounds__(256) void vsplitT_kernel(const float* __restrict__ v,
                                                      u16* __restrict__ vth, u16* __restrict__ vtl,
                                                      int N, int NP) {
  __shared__ float tile[64][65];
  const int bh = blockIdx.y;
  const int t0 = blockIdx.x * 64;
  const float* vb = v + (size_t)bh * N * 64;
#pragma unroll
  for (int r = 0; r < 16; ++r) {
    int idx = r * 256 + threadIdx.x;
    int tl = idx >> 6, d = idx & 63;
    int t = t0 + tl;
    tile[tl][d] = (t < N) ? vb[(size_t)t * 64 + d] : 0.f;
  }
  __syncthreads();
  u16* oh = vth + (size_t)bh * 64 * NP;
  u16* ol = vtl + (size_t)bh * 64 * NP;
#pragma unroll
  for (int r = 0; r < 16; ++r) {
    int idx = r * 256 + threadIdx.x;
    int d = idx >> 6, tl = idx & 63;
    int t = t0 + tl;
    if (t < NP) {
      float val = tile[tl][d];
      u16 h = f2bf(val);
      oh[(size_t)d * NP + t] = h;
      ol[(size_t)d * NP + t] = f2bf(val - bf2f(h));
    }
  }
}

// ---------------- bf16x3 emulated-fp32 GEMM: C = A(MxK) * W(NxK)^T + bias ----------------
__device__ __forceinline__ void stage_tile(const u16* __restrict__ g, u16* l,
                                           int row0, int rmax, int K, int k0, int tid) {
#pragma unroll
  for (int t = 0; t < 2; ++t) {
    int c = t * 256 + tid;
    int row = c >> 2, kc = (c & 3) << 3;
    int gr = row0 + row;
    if (gr > rmax) gr = rmax;
    const u16* gp = g + (size_t)gr * K + (k0 + kc);
    __builtin_amdgcn_global_load_lds((const __attribute__((address_space(1))) void*)gp,
                                     (__attribute__((address_space(3))) void*)(l + c * 8),
                                     16, 0, 0);
  }
}

template <int EPI>
__global__ __launch_bounds__(256) void gemm_bf16x3(
    const u16* __restrict__ Ah, const u16* __restrict__ Al,
    const u16* __restrict__ Bh, const u16* __restrict__ Bl,
    const float* __restrict__ bias,
    float* __restrict__ out0, float* __restrict__ out1, float* __restrict__ out2,
    int M, int Nn, int K, int Ntok) {
  __shared__ u16 lAh[4096], lAl[4096], lBh[4096], lBl[4096];
  const int tid = threadIdx.x;
  const int wid = tid >> 6, lane = tid & 63;
  const int wm = wid >> 1, wn = wid & 1;
  const int lg = lane >> 4, lm = lane & 15;
  const int mbase = blockIdx.y * 128, nbase = blockIdx.x * 128;

  f32x4 acc[4][4];
  const f32x4 zero = {0.f, 0.f, 0.f, 0.f};
#pragma unroll
  for (int a = 0; a < 4; ++a)
#pragma unroll
    for (int b = 0; b < 4; ++b) acc[a][b] = zero;

  for (int k0 = 0; k0 < K; k0 += 32) {
    stage_tile(Ah, lAh, mbase, M - 1, K, k0, tid);
    stage_tile(Al, lAl, mbase, M - 1, K, k0, tid);
    stage_tile(Bh, lBh, nbase, Nn - 1, K, k0, tid);
    stage_tile(Bl, lBl, nbase, Nn - 1, K, k0, tid);
    __syncthreads();
    bf16x8 afh[4], afl[4], bfh[4], bfl[4];
#pragma unroll
    for (int f = 0; f < 4; ++f) {
      afh[f] = *(const bf16x8*)&lAh[(wm * 64 + f * 16 + lm) * 32 + lg * 8];
      afl[f] = *(const bf16x8*)&lAl[(wm * 64 + f * 16 + lm) * 32 + lg * 8];
      bfh[f] = *(const bf16x8*)&lBh[(wn * 64 + f * 16 + lm) * 32 + lg * 8];
      bfl[f] = *(const bf16x8*)&lBl[(wn * 64 + f * 16 + lm) * 32 + lg * 8];
    }
#pragma unroll
    for (int fm = 0; fm < 4; ++fm)
#pragma unroll
      for (int fn = 0; fn < 4; ++fn) {
        acc[fm][fn] = MFMA16(afh[fm], bfh[fn], acc[fm][fn]);
        acc[fm][fn] = MFMA16(afh[fm], bfl[fn], acc[fm][fn]);
        acc[fm][fn] = MFMA16(afl[fm], bfh[fn], acc[fm][fn]);
      }
    __syncthreads();
  }

#pragma unroll
  for (int fm = 0; fm < 4; ++fm)
#pragma unroll
    for (int fn = 0; fn < 4; ++fn) {
      int col = nbase + wn * 64 + fn * 16 + lm;
      float bv = bias[col];
#pragma unroll
      for (int i = 0; i < 4; ++i) {
        int row = mbase + wm * 64 + fm * 16 + lg * 4 + i;
        if (row < M) {
          float v = acc[fm][fn][i] + bv;
          if (EPI == 1) {
            out0[(size_t)row * Nn + col] = v;
          } else {
            // fold softmax scale (1/8) and exp->exp2 conversion into q
            if (col < 1024) v *= 0.18033688011112042f;  // 0.125 * log2(e)
            int which = col >> 10, h2 = (col >> 6) & 15, d2 = col & 63;
            int b2 = row / Ntok, t2 = row - b2 * Ntok;
            float* dst = (which == 0) ? out0 : (which == 1) ? out1 : out2;
            dst[(((size_t)(b2 * 16 + h2)) * Ntok + t2) * 64 + d2] = v;
          }
        }
      }
    }
}

// ---------------- flash attention v3: LDS-shared K/V, 2-phase pipeline, 32 q-rows/wave ----------------
// K tile LDS layout: chunk (dk*4+lg)*32 + key holds K[kv+key][(dk*4+lg)*8 ..+8]  (4KB)
// V tile LDS layout: chunk lg*64 + d      holds V^T[d][kv+lg*8 ..+8]            (4KB)
template <bool DO_STAGE, bool TAIL>
__device__ __forceinline__ void attn_tile(
    int kv0, int kvn,
    const u16* Kc_h, const u16* Kc_l, const u16* Vc_h, const u16* Vc_l,
    u16* Kn_h, u16* Kn_l, u16* Vn_h, u16* Vn_l,
    const u16* kgb_h, const u16* kgb_l, const u16* vgb_h, const u16* vgb_l,
    int tid, int lg, int lm, int klo, int vlo,
    const bf16x8 (&qfh)[2][2], const bf16x8 (&qfl)[2][2],
    float (&m_)[2], float (&l_)[2], f32x4 (&oacc)[2][4],
    unsigned (*pexw)[4], int N) {
  if (DO_STAGE) {  // stage NEXT tile (other buffer) — latency hides under this tile's compute
    __builtin_amdgcn_global_load_lds(
        (const __attribute__((address_space(1))) void*)(kgb_h + (size_t)kvn * 64),
        (__attribute__((address_space(3))) void*)(Kn_h + tid * 8), 16, 0, 0);
    __builtin_amdgcn_global_load_lds(
        (const __attribute__((address_space(1))) void*)(kgb_l + (size_t)kvn * 64),
        (__attribute__((address_space(3))) void*)(Kn_l + tid * 8), 16, 0, 0);
    __builtin_amdgcn_global_load_lds(
        (const __attribute__((address_space(1))) void*)(vgb_h + kvn),
        (__attribute__((address_space(3))) void*)(Vn_h + tid * 8), 16, 0, 0);
    __builtin_amdgcn_global_load_lds(
        (const __attribute__((address_space(1))) void*)(vgb_l + kvn),
        (__attribute__((address_space(3))) void*)(Vn_l + tid * 8), 16, 0, 0);
  }

  const f32x4 zero = {0.f, 0.f, 0.f, 0.f};
  f32x4 s[2][2];
  s[0][0] = zero; s[0][1] = zero; s[1][0] = zero; s[1][1] = zero;
#pragma unroll
  for (int dk = 0; dk < 2; ++dk) {
    bf16x8 kh0 = *(const bf16x8*)&Kc_h[klo + dk * 1024];
    bf16x8 kl0 = *(const bf16x8*)&Kc_l[klo + dk * 1024];
    bf16x8 kh1 = *(const bf16x8*)&Kc_h[klo + dk * 1024 + 128];
    bf16x8 kl1 = *(const bf16x8*)&Kc_l[klo + dk * 1024 + 128];
#pragma unroll
    for (int qf = 0; qf < 2; ++qf) {
      s[qf][0] = MFMA16(kh0, qfh[qf][dk], s[qf][0]);
      s[qf][0] = MFMA16(kl0, qfh[qf][dk], s[qf][0]);
      s[qf][0] = MFMA16(kh0, qfl[qf][dk], s[qf][0]);
      s[qf][1] = MFMA16(kh1, qfh[qf][dk], s[qf][1]);
      s[qf][1] = MFMA16(kl1, qfh[qf][dk], s[qf][1]);
      s[qf][1] = MFMA16(kh1, qfl[qf][dk], s[qf][1]);
    }
  }
  if (TAIL) {
#pragma unroll
    for (int qf = 0; qf < 2; ++qf)
#pragma unroll
      for (int cf = 0; cf < 2; ++cf)
#pragma unroll
        for (int i = 0; i < 4; ++i)
          if (kv0 + cf * 16 + lg * 4 + i >= N) s[qf][cf][i] = -1e30f;
  }

  bf16x8 pb[2];
  const int ga = (lg & 1) * 2, gb = ga + 1;
  const int cfs2 = (lg >> 1) * 2;
#pragma unroll
  for (int qf = 0; qf < 2; ++qf) {
    float mx = fmaxf(fmaxf(fmaxf(s[qf][0][0], s[qf][0][1]), fmaxf(s[qf][0][2], s[qf][0][3])),
                     fmaxf(fmaxf(s[qf][1][0], s[qf][1][1]), fmaxf(s[qf][1][2], s[qf][1][3])));
    mx = fmaxf(mx, __shfl_xor(mx, 16));
    mx = fmaxf(mx, __shfl_xor(mx, 32));
    float mr = m_[qf];
    bool nore = __all(mx - mr <= 8.f) != 0;  // defer-max, THR=8 in log2 domain
    float mnew = nore ? mr : fmaxf(mr, mx);
    float p[8];
#pragma unroll
    for (int cf = 0; cf < 2; ++cf)
#pragma unroll
      for (int i = 0; i < 4; ++i)
        p[cf * 4 + i] = __builtin_amdgcn_exp2f(s[qf][cf][i] - mnew);
    float ps = ((p[0] + p[1]) + (p[2] + p[3])) + ((p[4] + p[5]) + (p[6] + p[7]));
    ps += __shfl_xor(ps, 16);
    ps += __shfl_xor(ps, 32);
    if (nore) {
      l_[qf] += ps;
    } else {
      float sc = __builtin_amdgcn_exp2f(mr - mnew);
      l_[qf] = l_[qf] * sc + ps;
      m_[qf] = mnew;
#pragma unroll
      for (int c = 0; c < 4; ++c)
#pragma unroll
        for (int i = 0; i < 4; ++i) oacc[qf][c][i] *= sc;
    }
    // pack P -> bf16, redistribute to B-frag via wave-private LDS (reused across qf; DS in-order)
    uint4 uw;
    uw.x = cvt_pk(p[0], p[1]);
    uw.y = cvt_pk(p[2], p[3]);
    uw.z = cvt_pk(p[4], p[5]);
    uw.w = cvt_pk(p[6], p[7]);
    *(uint4*)&pexw[lg * 16 + lm][0] = uw;
    uint2 r0 = *(const uint2*)&pexw[ga * 16 + lm][cfs2];
    uint2 r1 = *(const uint2*)&pexw[gb * 16 + lm][cfs2];
    uint4 pu = make_uint4(r0.x, r0.y, r1.x, r1.y);
    pb[qf] = __builtin_bit_cast(bf16x8, pu);
  }

#pragma unroll
  for (int c = 0; c < 4; ++c) {
    bf16x8 vh = *(const bf16x8*)&Vc_h[vlo + c * 128];
    bf16x8 vl = *(const bf16x8*)&Vc_l[vlo + c * 128];
    oacc[0][c] = MFMA16(vh, pb[0], oacc[0][c]);
    oacc[0][c] = MFMA16(vl, pb[0], oacc[0][c]);
    oacc[1][c] = MFMA16(vh, pb[1], oacc[1][c]);
    oacc[1][c] = MFMA16(vl, pb[1], oacc[1][c]);
  }
}

__global__ __launch_bounds__(256, 4) void attn_kernel(
    const u16* __restrict__ qh, const u16* __restrict__ ql,
    const u16* __restrict__ kh, const u16* __restrict__ kl,
    const u16* __restrict__ vth, const u16* __restrict__ vtl,
    u16* __restrict__ outh, u16* __restrict__ outl, int N, int NP) {
  __shared__ u16 K0h[2048], K0l[2048], V0h[2048], V0l[2048];
  __shared__ u16 K1h[2048], K1l[2048], V1h[2048], V1l[2048];
  __shared__ unsigned pexm[4][64][4];

  const int id = blockIdx.x;
  const int swz = (id & 7) * 136 + (id >> 3);  // XCD-bijective (1088 = 8*136)
  const int qblk = swz % 17;
  const int bh = swz / 17;
  const int b = bh >> 4, h = bh & 15;
  const int tid = threadIdx.x;
  const int wid = tid >> 6, lane = tid & 63;
  const int lg = lane >> 4, lm = lane & 15;
  const int qbase = qblk * 128 + wid * 32;
  const size_t qoff = (size_t)bh * N * 64;
  const size_t koff = (size_t)bh * NP * 64;
  const size_t voff = (size_t)bh * 64 * NP;

  // per-thread staging sources (K: chunk tid -> [key=tid&31][d-region=tid>>5]; V: [d=tid&63][kreg=tid>>6])
  const int rK = tid >> 5, jK = tid & 31;
  const int lgV = tid >> 6, dV = tid & 63;
  const u16* kgb_h = kh + koff + (size_t)jK * 64 + rK * 8;
  const u16* kgb_l = kl + koff + (size_t)jK * 64 + rK * 8;
  const u16* vgb_h = vth + voff + (size_t)dV * NP + lgV * 8;
  const u16* vgb_l = vtl + voff + (size_t)dV * NP + lgV * 8;
  const int klo = lg * 256 + lm * 8;  // + dk*1024 + cf*128
  const int vlo = lg * 512 + lm * 8;  // + c*128

  // Q fragments (2 per wave: rows qbase+lm, qbase+16+lm)
  bf16x8 qfh[2][2], qfl[2][2];
#pragma unroll
  for (int qf = 0; qf < 2; ++qf) {
    int qr = qbase + qf * 16 + lm;
    if (qr > N - 1) qr = N - 1;
    const u16* qp_h = qh + qoff + (size_t)qr * 64 + lg * 8;
    const u16* qp_l = ql + qoff + (size_t)qr * 64 + lg * 8;
    qfh[qf][0] = *(const bf16x8*)(qp_h);
    qfh[qf][1] = *(const bf16x8*)(qp_h + 32);
    qfl[qf][0] = *(const bf16x8*)(qp_l);
    qfl[qf][1] = *(const bf16x8*)(qp_l + 32);
  }

  const f32x4 zero = {0.f, 0.f, 0.f, 0.f};
  f32x4 oacc[2][4];
#pragma unroll
  for (int qf = 0; qf < 2; ++qf)
#pragma unroll
    for (int c = 0; c < 4; ++c) oacc[qf][c] = zero;
  float m_[2] = {-1e30f, -1e30f}, l_[2] = {0.f, 0.f};
  unsigned(*pexw)[4] = &pexm[wid][0];

  // prologue: stage tile 0 into buffer 0
  __builtin_amdgcn_global_load_lds(
      (const __attribute__((address_space(1))) void*)kgb_h,
      (__attribute__((address_space(3))) void*)(K0h + tid * 8), 16, 0, 0);
  __builtin_amdgcn_global_load_lds(
      (const __attribute__((address_space(1))) void*)kgb_l,
      (__attribute__((address_space(3))) void*)(K0l + tid * 8), 16, 0, 0);
  __builtin_amdgcn_global_load_lds(
      (const __attribute__((address_space(1))) void*)vgb_h,
      (__attribute__((address_space(3))) void*)(V0h + tid * 8), 16, 0, 0);
  __builtin_amdgcn_global_load_lds(
      (const __attribute__((address_space(1))) void*)vgb_l,
      (__attribute__((address_space(3))) void*)(V0l + tid * 8), 16, 0, 0);
  asm volatile("s_waitcnt vmcnt(0)" ::: "memory");
  __builtin_amdgcn_s_barrier();

  // main loop: tiles 0..63 (2-unrolled over statically distinct buffers), tile 64 = tail
  for (int t = 0; t + 2 < 65; t += 2) {
    attn_tile<true, false>(t * 32, (t + 1) * 32, K0h, K0l, V0h, V0l, K1h, K1l, V1h, V1l,
                           kgb_h, kgb_l, vgb_h, vgb_l, tid, lg, lm, klo, vlo,
                           qfh, qfl, m_, l_, oacc, pexw, N);
    asm volatile("s_waitcnt vmcnt(0)" ::: "memory");
    __builtin_amdgcn_s_barrier();
    attn_tile<true, false>((t + 1) * 32, (t + 2) * 32, K1h, K1l, V1h, V1l, K0h, K0l, V0h, V0l,
                           kgb_h, kgb_l, vgb_h, vgb_l, tid, lg, lm, klo, vlo,
                           qfh, qfl, m_, l_, oacc, pexw, N);
    asm volatile("s_waitcnt vmcnt(0)" ::: "memory");
    __builtin_amdgcn_s_barrier();
  }
  attn_tile<false, true>(64 * 32, 0, K0h, K0l, V0h, V0l, K1h, K1l, V1h, V1l,
                         kgb_h, kgb_l, vgb_h, vgb_l, tid, lg, lm, klo, vlo,
                         qfh, qfl, m_, l_, oacc, pexw, N);

  // epilogue: O/l -> bf16 hi/lo directly (feeds final GEMM)
#pragma unroll
  for (int qf = 0; qf < 2; ++qf) {
    int t = qbase + qf * 16 + lm;
    if (t < N) {
      float rl = 1.f / l_[qf];
      size_t rowoff = ((size_t)(b * N + t)) * 1024 + h * 64 + lg * 4;
#pragma unroll
      for (int c = 0; c < 4; ++c) {
        float v0 = oacc[qf][c][0] * rl, v1 = oacc[qf][c][1] * rl;
        float v2 = oacc[qf][c][2] * rl, v3 = oacc[qf][c][3] * rl;
        unsigned h01 = cvt_pk(v0, v1), h23 = cvt_pk(v2, v3);
        unsigned l01 = cvt_pk(v0 - __uint_as_float(h01 << 16),
                              v1 - __uint_as_float(h01 & 0xffff0000u));
        unsigned l23 = cvt_pk(v2 - __uint_as_float(h23 << 16),
                              v3 - __uint_as_float(h23 & 0xffff0000u));
        *(uint2*)(outh + rowoff + c * 16) = make_uint2(h01, h23);
        *(uint2*)(outl + rowoff + c * 16) = make_uint2(l01, l23);
      }
    }
  }
}

// ---------------- orchestration ----------------
extern "C" void kernel_launch(void* const* d_in, const int* in_sizes, int n_in,
                              void* d_out, int out_size, void* d_ws, size_t ws_size,
                              hipStream_t stream) {
  const float* x     = (const float*)d_in[0];
  const int*   pos   = (const int*)  d_in[1];
  const float* w_qkv = (const float*)d_in[2];
  const float* b_qkv = (const float*)d_in[3];
  const float* w_fc  = (const float*)d_in[4];
  const float* b_fc  = (const float*)d_in[5];
  (void)in_sizes; (void)n_in; (void)out_size; (void)ws_size;

  const int B = 4, N = 2049, NP = 2080;
  const long EL = (long)B * N * 1024;       // 8,392,704
  const long ELP = (long)B * 16 * NP * 64;  // padded K elems

  char* base = (char*)d_ws;
  size_t off = 0;
  auto alloc = [&](size_t bytes) -> void* {
    void* p = base + off;
    off += (bytes + 255) & ~(size_t)255;
    return p;
  };
  float* qf = (float*)alloc(EL * 4);
  float* kf = (float*)alloc(EL * 4);
  float* vf = (float*)alloc(EL * 4);
  u16* qhh = (u16*)alloc(EL * 2);
  u16* qll = (u16*)alloc(EL * 2);
  u16* khh = (u16*)alloc(ELP * 2);
  u16* kll = (u16*)alloc(ELP * 2);
  u16* vth = (u16*)alloc((size_t)64 * 64 * NP * 2);
  u16* vtl = (u16*)alloc((size_t)64 * 64 * NP * 2);
  u16* xh  = (u16*)alloc(EL * 2);
  u16* xl  = (u16*)alloc(EL * 2);
  u16* wqh = (u16*)alloc((size_t)3072 * 1024 * 2);
  u16* wql = (u16*)alloc((size_t)3072 * 1024 * 2);
  u16* wfh = (u16*)alloc((size_t)1024 * 1024 * 2);
  u16* wfl = (u16*)alloc((size_t)1024 * 1024 * 2);

  // 1. split inputs to bf16 hi/lo
  split_kernel<<<2048, 256, 0, stream>>>(x, xh, xl, EL / 4);
  split_kernel<<<1024, 256, 0, stream>>>(w_qkv, wqh, wql, (long)3072 * 1024 / 4);
  split_kernel<<<512, 256, 0, stream>>>(w_fc, wfh, wfl, (long)1024 * 1024 / 4);
  // 2. fused QKV projection -> q,k,v fp32 in (B,H,N,hd); q pre-scaled for exp2 softmax
  gemm_bf16x3<0><<<dim3(24, 65), 256, 0, stream>>>(xh, xl, wqh, wql, b_qkv,
                                                   qf, kf, vf, 8196, 3072, 1024, N);
  // 3. RoPE + split q (N tokens), k (padded to NP)
  rope_split_kernel<<<2048, 256, 0, stream>>>(qf, kf, pos, qhh, qll, khh, kll, B, N, NP);
  // 4. transpose+split+pad v
  vsplitT_kernel<<<dim3((NP + 63) / 64, 64), 256, 0, stream>>>(vf, vth, vtl, N, NP);
  // 5. flash attention -> bf16 hi/lo (B,N,D), reusing xh/xl
  attn_kernel<<<dim3(1088), 256, 0, stream>>>(qhh, qll, khh, kll, vth, vtl, xh, xl, N, NP);
  // 6. output projection -> d_out
  gemm_bf16x3<1><<<dim3(8, 65), 256, 0, stream>>>(xh, xl, wfh, wfl, b_fc,
                                                  (float*)d_out, nullptr, nullptr,
                                                  8196, 1024, 1024, N);
}

// Round 4
// 671.794 us; speedup vs baseline: 1.9839x; 1.0407x over previous
//
#include <hip/hip_runtime.h>

typedef unsigned short u16;
typedef __attribute__((ext_vector_type(8))) short bf16x8;
typedef __attribute__((ext_vector_type(4))) float f32x4;

#define MFMA16(a, b, c) __builtin_amdgcn_mfma_f32_16x16x32_bf16((a), (b), (c), 0, 0, 0)

__device__ __forceinline__ u16 f2bf(float f) {
  unsigned u = __float_as_uint(f);
  return (u16)((u + 0x7FFFu + ((u >> 16) & 1u)) >> 16);
}
__device__ __forceinline__ float bf2f(u16 h) { return __uint_as_float(((unsigned)h) << 16); }
// packed f32x2 -> bf16x2 (RNE), lo word = a, hi word = b
__device__ __forceinline__ unsigned cvt_pk(float a, float b) {
  unsigned r;
  asm("v_cvt_pk_bf16_f32 %0, %1, %2" : "=v"(r) : "v"(a), "v"(b));
  return r;
}

// ---------------- elementwise split: fp32 -> bf16 hi + bf16 lo ----------------
__global__ void split_kernel(const float* __restrict__ in, u16* __restrict__ hi,
                             u16* __restrict__ lo, long n4) {
  long stride = (long)gridDim.x * blockDim.x;
  for (long i = (long)blockIdx.x * blockDim.x + threadIdx.x; i < n4; i += stride) {
    float4 v = ((const float4*)in)[i];
    ushort4 h, l;
    h.x = f2bf(v.x); l.x = f2bf(v.x - bf2f(h.x));
    h.y = f2bf(v.y); l.y = f2bf(v.y - bf2f(h.y));
    h.z = f2bf(v.z); l.z = f2bf(v.z - bf2f(h.z));
    h.w = f2bf(v.w); l.w = f2bf(v.w - bf2f(h.w));
    ((ushort4*)hi)[i] = h;
    ((ushort4*)lo)[i] = l;
  }
}

// ---------------- cos/sin table: (b, t-1, i) -> float2(c,s); 16 heads share positions ----------------
__global__ void cs_table_kernel(const int* __restrict__ pos, float2* __restrict__ cst) {
  int idx = blockIdx.x * 256 + threadIdx.x;  // exactly B*2048*32 threads
  int i = idx & 31;
  int r = idx >> 5;
  int ti = r & 2047;
  int b = r >> 11;
  int p = pos[b * 2048 + ti];
  // replicate reference fp32 rounding of freq and angle, then exact trig
  float fr = (float)pow(10000.0, -(double)i / 32.0);
  float angf = (float)p * fr;
  double sd, cd;
  sincos((double)angf, &sd, &cd);
  cst[idx] = make_float2((float)cd, (float)sd);
}

// ---------------- K pad rows [N, NP): zero ----------------
__global__ void kpad_kernel(u16* __restrict__ kh, u16* __restrict__ kl, int N, int NP) {
  const int per_bh = (NP - N) * 32;  // uints per bh (31*64 u16 / 2)
  int idx = blockIdx.x * 256 + threadIdx.x;
  if (idx >= 64 * per_bh) return;
  int bh = idx / per_bh, r = idx - bh * per_bh;
  size_t u = (((size_t)bh * NP + N) * 64 >> 1) + r;
  ((unsigned*)kh)[u] = 0;
  ((unsigned*)kl)[u] = 0;
}

// ---------------- V transpose: bf16 [bh][N][64] -> [bh][64][NP], zero-padded ----------------
__global__ __launch_bounds__(256) void vtransT_kernel(const u16* __restrict__ vh_,
                                                      const u16* __restrict__ vl_,
                                                      u16* __restrict__ oth, u16* __restrict__ otl,
                                                      int N, int NP) {
  __shared__ u16 th[64][72], tl[64][72];
  const int bh = blockIdx.y;
  const int t0 = blockIdx.x * 64;
  const u16* ih = vh_ + (size_t)bh * N * 64;
  const u16* il = vl_ + (size_t)bh * N * 64;
#pragma unroll
  for (int p = 0; p < 4; ++p) {
    int idx = p * 256 + threadIdx.x;  // 1024 chunks of 4 u16
    int tloc = idx >> 4, c = (idx & 15) * 4;
    int t = t0 + tloc;
    ushort4 a = make_ushort4(0, 0, 0, 0), b4 = make_ushort4(0, 0, 0, 0);
    if (t < N) {
      a = *(const ushort4*)(ih + (size_t)t * 64 + c);
      b4 = *(const ushort4*)(il + (size_t)t * 64 + c);
    }
    *(ushort4*)&th[tloc][c] = a;
    *(ushort4*)&tl[tloc][c] = b4;
  }
  __syncthreads();
  u16* oh = oth + (size_t)bh * 64 * NP;
  u16* ol = otl + (size_t)bh * 64 * NP;
#pragma unroll
  for (int p = 0; p < 4; ++p) {
    int idx = p * 256 + threadIdx.x;  // 1024 chunks: d (64) x tquad (16)
    int d = idx >> 4, tq = (idx & 15) * 4;
    int t = t0 + tq;
    if (t < NP) {
      ushort4 a, b4;
      a.x = th[tq + 0][d]; a.y = th[tq + 1][d]; a.z = th[tq + 2][d]; a.w = th[tq + 3][d];
      b4.x = tl[tq + 0][d]; b4.y = tl[tq + 1][d]; b4.z = tl[tq + 2][d]; b4.w = tl[tq + 3][d];
      *(ushort4*)(oh + (size_t)d * NP + t) = a;
      *(ushort4*)(ol + (size_t)d * NP + t) = b4;
    }
  }
}

// ---------------- bf16x3 emulated-fp32 GEMM: C = A(MxK) * W(NxK)^T + bias ----------------
// EPI 0: fused RoPE (table) + bf16 hi/lo split; q scaled; q/k row-major per head, v row-major.
// EPI 1: fp32 row-major out.
__device__ __forceinline__ void stage_tile(const u16* __restrict__ g, u16* l,
                                           int row0, int rmax, int K, int k0, int tid) {
#pragma unroll
  for (int t = 0; t < 2; ++t) {
    int c = t * 256 + tid;
    int row = c >> 2, kc = (c & 3) << 3;
    int gr = row0 + row;
    if (gr > rmax) gr = rmax;
    const u16* gp = g + (size_t)gr * K + (k0 + kc);
    __builtin_amdgcn_global_load_lds((const __attribute__((address_space(1))) void*)gp,
                                     (__attribute__((address_space(3))) void*)(l + c * 8),
                                     16, 0, 0);
  }
}

template <int EPI>
__global__ __launch_bounds__(256) void gemm_bf16x3(
    const u16* __restrict__ Ah, const u16* __restrict__ Al,
    const u16* __restrict__ Bh, const u16* __restrict__ Bl,
    const float* __restrict__ bias, const float2* __restrict__ cst,
    float* __restrict__ outf,
    u16* __restrict__ oqh, u16* __restrict__ oql,
    u16* __restrict__ okh, u16* __restrict__ okl,
    u16* __restrict__ ovh, u16* __restrict__ ovl,
    int M, int Nn, int K, int Ntok, int NP) {
  __shared__ u16 lAh[4096], lAl[4096], lBh[4096], lBl[4096];
  const int tid = threadIdx.x;
  const int wid = tid >> 6, lane = tid & 63;
  const int wm = wid >> 1, wn = wid & 1;
  const int lg = lane >> 4, lm = lane & 15;
  const int mbase = blockIdx.y * 128, nbase = blockIdx.x * 128;

  f32x4 acc[4][4];
  const f32x4 zero = {0.f, 0.f, 0.f, 0.f};
#pragma unroll
  for (int a = 0; a < 4; ++a)
#pragma unroll
    for (int b = 0; b < 4; ++b) acc[a][b] = zero;

  for (int k0 = 0; k0 < K; k0 += 32) {
    stage_tile(Ah, lAh, mbase, M - 1, K, k0, tid);
    stage_tile(Al, lAl, mbase, M - 1, K, k0, tid);
    stage_tile(Bh, lBh, nbase, Nn - 1, K, k0, tid);
    stage_tile(Bl, lBl, nbase, Nn - 1, K, k0, tid);
    __syncthreads();
    bf16x8 afh[4], afl[4], bfh[4], bfl[4];
#pragma unroll
    for (int f = 0; f < 4; ++f) {
      afh[f] = *(const bf16x8*)&lAh[(wm * 64 + f * 16 + lm) * 32 + lg * 8];
      afl[f] = *(const bf16x8*)&lAl[(wm * 64 + f * 16 + lm) * 32 + lg * 8];
      bfh[f] = *(const bf16x8*)&lBh[(wn * 64 + f * 16 + lm) * 32 + lg * 8];
      bfl[f] = *(const bf16x8*)&lBl[(wn * 64 + f * 16 + lm) * 32 + lg * 8];
    }
#pragma unroll
    for (int fm = 0; fm < 4; ++fm)
#pragma unroll
      for (int fn = 0; fn < 4; ++fn) {
        acc[fm][fn] = MFMA16(afh[fm], bfh[fn], acc[fm][fn]);
        acc[fm][fn] = MFMA16(afh[fm], bfl[fn], acc[fm][fn]);
        acc[fm][fn] = MFMA16(afl[fm], bfh[fn], acc[fm][fn]);
      }
    __syncthreads();
  }

  // which output region (block-uniform: 128-col tiles never straddle 1024 boundaries)
  const int which = (EPI == 0) ? (nbase >> 10) : 1;
  const bool odd = (lm & 1);

#pragma unroll
  for (int fm = 0; fm < 4; ++fm)
#pragma unroll
    for (int fn = 0; fn < 4; ++fn) {
      int col = nbase + wn * 64 + fn * 16 + lm;
      float bv = bias[col];
      int h2 = (col >> 6) & 15, d2 = col & 63;
#pragma unroll
      for (int i = 0; i < 4; ++i) {
        int row = mbase + wm * 64 + fm * 16 + lg * 4 + i;
        float v = acc[fm][fn][i] + bv;
        float partner = __shfl_xor(v, 1);  // neighbor column (re<->im), uniform exec
        if (row < M) {
          if (EPI == 1) {
            outf[(size_t)row * Nn + col] = v;
          } else {
            int b2 = row / Ntok, t2 = row - b2 * Ntok;
            int bh2 = b2 * 16 + h2;
            if (which == 2) {  // v: plain split, row-major
              u16 hh = f2bf(v);
              ovh[((size_t)bh2 * Ntok + t2) * 64 + d2] = hh;
              ovl[((size_t)bh2 * Ntok + t2) * 64 + d2] = f2bf(v - bf2f(hh));
            } else {
              // rope: even lane = re, odd lane = im
              float out = v;
              if (t2 > 0) {
                float2 cs = cst[((size_t)(b2 << 11) + (t2 - 1)) * 32 + (d2 >> 1)];
                out = v * cs.x + (odd ? partner * cs.y : -partner * cs.y);
              }
              if (which == 0) {  // q: fold softmax scale & exp2 conversion
                out *= 0.18033688011112042f;  // 0.125 * log2(e)
                u16 hh = f2bf(out);
                oqh[((size_t)bh2 * Ntok + t2) * 64 + d2] = hh;
                oql[((size_t)bh2 * Ntok + t2) * 64 + d2] = f2bf(out - bf2f(hh));
              } else {  // k: padded row allocation [bh][NP][64]
                u16 hh = f2bf(out);
                okh[((size_t)bh2 * NP + t2) * 64 + d2] = hh;
                okl[((size_t)bh2 * NP + t2) * 64 + d2] = f2bf(out - bf2f(hh));
              }
            }
          }
        }
      }
    }
}

// ---------------- flash attention v3: LDS-shared K/V, 2-phase pipeline, 32 q-rows/wave ----------------
template <bool DO_STAGE, bool TAIL>
__device__ __forceinline__ void attn_tile(
    int kv0, int kvn,
    const u16* Kc_h, const u16* Kc_l, const u16* Vc_h, const u16* Vc_l,
    u16* Kn_h, u16* Kn_l, u16* Vn_h, u16* Vn_l,
    const u16* kgb_h, const u16* kgb_l, const u16* vgb_h, const u16* vgb_l,
    int tid, int lg, int lm, int klo, int vlo,
    const bf16x8 (&qfh)[2][2], const bf16x8 (&qfl)[2][2],
    float (&m_)[2], float (&l_)[2], f32x4 (&oacc)[2][4],
    unsigned (*pexw)[4], int N) {
  if (DO_STAGE) {  // stage NEXT tile (other buffer) — latency hides under this tile's compute
    __builtin_amdgcn_global_load_lds(
        (const __attribute__((address_space(1))) void*)(kgb_h + (size_t)kvn * 64),
        (__attribute__((address_space(3))) void*)(Kn_h + tid * 8), 16, 0, 0);
    __builtin_amdgcn_global_load_lds(
        (const __attribute__((address_space(1))) void*)(kgb_l + (size_t)kvn * 64),
        (__attribute__((address_space(3))) void*)(Kn_l + tid * 8), 16, 0, 0);
    __builtin_amdgcn_global_load_lds(
        (const __attribute__((address_space(1))) void*)(vgb_h + kvn),
        (__attribute__((address_space(3))) void*)(Vn_h + tid * 8), 16, 0, 0);
    __builtin_amdgcn_global_load_lds(
        (const __attribute__((address_space(1))) void*)(vgb_l + kvn),
        (__attribute__((address_space(3))) void*)(Vn_l + tid * 8), 16, 0, 0);
  }

  const f32x4 zero = {0.f, 0.f, 0.f, 0.f};
  f32x4 s[2][2];
  s[0][0] = zero; s[0][1] = zero; s[1][0] = zero; s[1][1] = zero;
  __builtin_amdgcn_s_setprio(1);
#pragma unroll
  for (int dk = 0; dk < 2; ++dk) {
    bf16x8 kh0 = *(const bf16x8*)&Kc_h[klo + dk * 1024];
    bf16x8 kl0 = *(const bf16x8*)&Kc_l[klo + dk * 1024];
    bf16x8 kh1 = *(const bf16x8*)&Kc_h[klo + dk * 1024 + 128];
    bf16x8 kl1 = *(const bf16x8*)&Kc_l[klo + dk * 1024 + 128];
#pragma unroll
    for (int qf = 0; qf < 2; ++qf) {
      s[qf][0] = MFMA16(kh0, qfh[qf][dk], s[qf][0]);
      s[qf][0] = MFMA16(kl0, qfh[qf][dk], s[qf][0]);
      s[qf][0] = MFMA16(kh0, qfl[qf][dk], s[qf][0]);
      s[qf][1] = MFMA16(kh1, qfh[qf][dk], s[qf][1]);
      s[qf][1] = MFMA16(kl1, qfh[qf][dk], s[qf][1]);
      s[qf][1] = MFMA16(kh1, qfl[qf][dk], s[qf][1]);
    }
  }
  __builtin_amdgcn_s_setprio(0);
  if (TAIL) {
#pragma unroll
    for (int qf = 0; qf < 2; ++qf)
#pragma unroll
      for (int cf = 0; cf < 2; ++cf)
#pragma unroll
        for (int i = 0; i < 4; ++i)
          if (kv0 + cf * 16 + lg * 4 + i >= N) s[qf][cf][i] = -1e30f;
  }

  bf16x8 pb[2];
  const int ga = (lg & 1) * 2, gb = ga + 1;
  const int cfs2 = (lg >> 1) * 2;
#pragma unroll
  for (int qf = 0; qf < 2; ++qf) {
    float mx = fmaxf(fmaxf(fmaxf(s[qf][0][0], s[qf][0][1]), fmaxf(s[qf][0][2], s[qf][0][3])),
                     fmaxf(fmaxf(s[qf][1][0], s[qf][1][1]), fmaxf(s[qf][1][2], s[qf][1][3])));
    mx = fmaxf(mx, __shfl_xor(mx, 16));
    mx = fmaxf(mx, __shfl_xor(mx, 32));
    float mr = m_[qf];
    bool nore = __all(mx - mr <= 8.f) != 0;  // defer-max, THR=8 in log2 domain
    float mnew = nore ? mr : fmaxf(mr, mx);
    float p[8];
#pragma unroll
    for (int cf = 0; cf < 2; ++cf)
#pragma unroll
      for (int i = 0; i < 4; ++i)
        p[cf * 4 + i] = __builtin_amdgcn_exp2f(s[qf][cf][i] - mnew);
    float ps = ((p[0] + p[1]) + (p[2] + p[3])) + ((p[4] + p[5]) + (p[6] + p[7]));
    ps += __shfl_xor(ps, 16);
    ps += __shfl_xor(ps, 32);
    if (nore) {
      l_[qf] += ps;
    } else {
      float sc = __builtin_amdgcn_exp2f(mr - mnew);
      l_[qf] = l_[qf] * sc + ps;
      m_[qf] = mnew;
#pragma unroll
      for (int c = 0; c < 4; ++c)
#pragma unroll
        for (int i = 0; i < 4; ++i) oacc[qf][c][i] *= sc;
    }
    // pack P -> bf16, redistribute to B-frag via wave-private LDS (DS ops in-order per wave)
    uint4 uw;
    uw.x = cvt_pk(p[0], p[1]);
    uw.y = cvt_pk(p[2], p[3]);
    uw.z = cvt_pk(p[4], p[5]);
    uw.w = cvt_pk(p[6], p[7]);
    *(uint4*)&pexw[lg * 16 + lm][0] = uw;
    uint2 r0 = *(const uint2*)&pexw[ga * 16 + lm][cfs2];
    uint2 r1 = *(const uint2*)&pexw[gb * 16 + lm][cfs2];
    uint4 pu = make_uint4(r0.x, r0.y, r1.x, r1.y);
    pb[qf] = __builtin_bit_cast(bf16x8, pu);
  }

  __builtin_amdgcn_s_setprio(1);
#pragma unroll
  for (int c = 0; c < 4; ++c) {
    bf16x8 vh = *(const bf16x8*)&Vc_h[vlo + c * 128];
    bf16x8 vl = *(const bf16x8*)&Vc_l[vlo + c * 128];
    oacc[0][c] = MFMA16(vh, pb[0], oacc[0][c]);
    oacc[0][c] = MFMA16(vl, pb[0], oacc[0][c]);
    oacc[1][c] = MFMA16(vh, pb[1], oacc[1][c]);
    oacc[1][c] = MFMA16(vl, pb[1], oacc[1][c]);
  }
  __builtin_amdgcn_s_setprio(0);
}

__global__ __launch_bounds__(256, 4) void attn_kernel(
    const u16* __restrict__ qh, const u16* __restrict__ ql,
    const u16* __restrict__ kh, const u16* __restrict__ kl,
    const u16* __restrict__ vth, const u16* __restrict__ vtl,
    u16* __restrict__ outh, u16* __restrict__ outl, int N, int NP) {
  __shared__ u16 K0h[2048], K0l[2048], V0h[2048], V0l[2048];
  __shared__ u16 K1h[2048], K1l[2048], V1h[2048], V1l[2048];
  __shared__ unsigned pexm[4][64][4];

  const int id = blockIdx.x;
  const int swz = (id & 7) * 136 + (id >> 3);  // XCD-bijective (1088 = 8*136)
  const int qblk = swz % 17;
  const int bh = swz / 17;
  const int b = bh >> 4, h = bh & 15;
  const int tid = threadIdx.x;
  const int wid = tid >> 6, lane = tid & 63;
  const int lg = lane >> 4, lm = lane & 15;
  const int qbase = qblk * 128 + wid * 32;
  const size_t qoff = (size_t)bh * N * 64;
  const size_t koff = (size_t)bh * NP * 64;
  const size_t voff = (size_t)bh * 64 * NP;

  const int rK = tid >> 5, jK = tid & 31;
  const int lgV = tid >> 6, dV = tid & 63;
  const u16* kgb_h = kh + koff + (size_t)jK * 64 + rK * 8;
  const u16* kgb_l = kl + koff + (size_t)jK * 64 + rK * 8;
  const u16* vgb_h = vth + voff + (size_t)dV * NP + lgV * 8;
  const u16* vgb_l = vtl + voff + (size_t)dV * NP + lgV * 8;
  const int klo = lg * 256 + lm * 8;  // + dk*1024 + cf*128
  const int vlo = lg * 512 + lm * 8;  // + c*128

  bf16x8 qfh[2][2], qfl[2][2];
#pragma unroll
  for (int qf = 0; qf < 2; ++qf) {
    int qr = qbase + qf * 16 + lm;
    if (qr > N - 1) qr = N - 1;
    const u16* qp_h = qh + qoff + (size_t)qr * 64 + lg * 8;
    const u16* qp_l = ql + qoff + (size_t)qr * 64 + lg * 8;
    qfh[qf][0] = *(const bf16x8*)(qp_h);
    qfh[qf][1] = *(const bf16x8*)(qp_h + 32);
    qfl[qf][0] = *(const bf16x8*)(qp_l);
    qfl[qf][1] = *(const bf16x8*)(qp_l + 32);
  }

  const f32x4 zero = {0.f, 0.f, 0.f, 0.f};
  f32x4 oacc[2][4];
#pragma unroll
  for (int qf = 0; qf < 2; ++qf)
#pragma unroll
    for (int c = 0; c < 4; ++c) oacc[qf][c] = zero;
  float m_[2] = {-1e30f, -1e30f}, l_[2] = {0.f, 0.f};
  unsigned(*pexw)[4] = &pexm[wid][0];

  __builtin_amdgcn_global_load_lds(
      (const __attribute__((address_space(1))) void*)kgb_h,
      (__attribute__((address_space(3))) void*)(K0h + tid * 8), 16, 0, 0);
  __builtin_amdgcn_global_load_lds(
      (const __attribute__((address_space(1))) void*)kgb_l,
      (__attribute__((address_space(3))) void*)(K0l + tid * 8), 16, 0, 0);
  __builtin_amdgcn_global_load_lds(
      (const __attribute__((address_space(1))) void*)vgb_h,
      (__attribute__((address_space(3))) void*)(V0h + tid * 8), 16, 0, 0);
  __builtin_amdgcn_global_load_lds(
      (const __attribute__((address_space(1))) void*)vgb_l,
      (__attribute__((address_space(3))) void*)(V0l + tid * 8), 16, 0, 0);
  asm volatile("s_waitcnt vmcnt(0)" ::: "memory");
  __builtin_amdgcn_s_barrier();

  for (int t = 0; t + 2 < 65; t += 2) {
    attn_tile<true, false>(t * 32, (t + 1) * 32, K0h, K0l, V0h, V0l, K1h, K1l, V1h, V1l,
                           kgb_h, kgb_l, vgb_h, vgb_l, tid, lg, lm, klo, vlo,
                           qfh, qfl, m_, l_, oacc, pexw, N);
    asm volatile("s_waitcnt vmcnt(0)" ::: "memory");
    __builtin_amdgcn_s_barrier();
    attn_tile<true, false>((t + 1) * 32, (t + 2) * 32, K1h, K1l, V1h, V1l, K0h, K0l, V0h, V0l,
                           kgb_h, kgb_l, vgb_h, vgb_l, tid, lg, lm, klo, vlo,
                           qfh, qfl, m_, l_, oacc, pexw, N);
    asm volatile("s_waitcnt vmcnt(0)" ::: "memory");
    __builtin_amdgcn_s_barrier();
  }
  attn_tile<false, true>(64 * 32, 0, K0h, K0l, V0h, V0l, K1h, K1l, V1h, V1l,
                         kgb_h, kgb_l, vgb_h, vgb_l, tid, lg, lm, klo, vlo,
                         qfh, qfl, m_, l_, oacc, pexw, N);

#pragma unroll
  for (int qf = 0; qf < 2; ++qf) {
    int t = qbase + qf * 16 + lm;
    if (t < N) {
      float rl = 1.f / l_[qf];
      size_t rowoff = ((size_t)(b * N + t)) * 1024 + h * 64 + lg * 4;
#pragma unroll
      for (int c = 0; c < 4; ++c) {
        float v0 = oacc[qf][c][0] * rl, v1 = oacc[qf][c][1] * rl;
        float v2 = oacc[qf][c][2] * rl, v3 = oacc[qf][c][3] * rl;
        unsigned h01 = cvt_pk(v0, v1), h23 = cvt_pk(v2, v3);
        unsigned l01 = cvt_pk(v0 - __uint_as_float(h01 << 16),
                              v1 - __uint_as_float(h01 & 0xffff0000u));
        unsigned l23 = cvt_pk(v2 - __uint_as_float(h23 << 16),
                              v3 - __uint_as_float(h23 & 0xffff0000u));
        *(uint2*)(outh + rowoff + c * 16) = make_uint2(h01, h23);
        *(uint2*)(outl + rowoff + c * 16) = make_uint2(l01, l23);
      }
    }
  }
}

// ---------------- orchestration ----------------
extern "C" void kernel_launch(void* const* d_in, const int* in_sizes, int n_in,
                              void* d_out, int out_size, void* d_ws, size_t ws_size,
                              hipStream_t stream) {
  const float* x     = (const float*)d_in[0];
  const int*   pos   = (const int*)  d_in[1];
  const float* w_qkv = (const float*)d_in[2];
  const float* b_qkv = (const float*)d_in[3];
  const float* w_fc  = (const float*)d_in[4];
  const float* b_fc  = (const float*)d_in[5];
  (void)in_sizes; (void)n_in; (void)out_size; (void)ws_size;

  const int B = 4, N = 2049, NP = 2080;
  const long EL = (long)B * N * 1024;       // 8,392,704
  const long ELP = (long)B * 16 * NP * 64;  // padded K elems

  char* base = (char*)d_ws;
  size_t off = 0;
  auto alloc = [&](size_t bytes) -> void* {
    void* p = base + off;
    off += (bytes + 255) & ~(size_t)255;
    return p;
  };
  u16* qhh = (u16*)alloc(EL * 2);
  u16* qll = (u16*)alloc(EL * 2);
  u16* khh = (u16*)alloc(ELP * 2);
  u16* kll = (u16*)alloc(ELP * 2);
  u16* vbh = (u16*)alloc(EL * 2);
  u16* vbl = (u16*)alloc(EL * 2);
  u16* vth = (u16*)alloc((size_t)64 * 64 * NP * 2);
  u16* vtl = (u16*)alloc((size_t)64 * 64 * NP * 2);
  u16* xh  = (u16*)alloc(EL * 2);
  u16* xl  = (u16*)alloc(EL * 2);
  u16* wqh = (u16*)alloc((size_t)3072 * 1024 * 2);
  u16* wql = (u16*)alloc((size_t)3072 * 1024 * 2);
  u16* wfh = (u16*)alloc((size_t)1024 * 1024 * 2);
  u16* wfl = (u16*)alloc((size_t)1024 * 1024 * 2);
  float2* cst = (float2*)alloc((size_t)B * 2048 * 32 * 8);

  // 1. split inputs; build cos/sin table (one fp64 sincos per (b,t,i), shared by 16 heads)
  split_kernel<<<2048, 256, 0, stream>>>(x, xh, xl, EL / 4);
  split_kernel<<<1024, 256, 0, stream>>>(w_qkv, wqh, wql, (long)3072 * 1024 / 4);
  split_kernel<<<512, 256, 0, stream>>>(w_fc, wfh, wfl, (long)1024 * 1024 / 4);
  cs_table_kernel<<<(B * 2048 * 32) / 256, 256, 0, stream>>>(pos, cst);
  // 2. fused QKV projection with fused RoPE + split epilogue
  gemm_bf16x3<0><<<dim3(24, 65), 256, 0, stream>>>(xh, xl, wqh, wql, b_qkv, cst, nullptr,
                                                   qhh, qll, khh, kll, vbh, vbl,
                                                   8196, 3072, 1024, N, NP);
  // 3. pad K rows [N,NP); transpose+pad V (bf16 -> [bh][64][NP])
  kpad_kernel<<<(64 * (NP - N) * 32 + 255) / 256, 256, 0, stream>>>(khh, kll, N, NP);
  vtransT_kernel<<<dim3((NP + 63) / 64, 64), 256, 0, stream>>>(vbh, vbl, vth, vtl, N, NP);
  // 4. flash attention -> bf16 hi/lo (B,N,D), reusing xh/xl
  attn_kernel<<<dim3(1088), 256, 0, stream>>>(qhh, qll, khh, kll, vth, vtl, xh, xl, N, NP);
  // 5. output projection -> d_out
  gemm_bf16x3<1><<<dim3(8, 65), 256, 0, stream>>>(xh, xl, wfh, wfl, b_fc, nullptr,
                                                  (float*)d_out, nullptr, nullptr, nullptr,
                                                  nullptr, nullptr, nullptr,
                                                  8196, 1024, 1024, N, NP);
}

// Round 5
// 666.874 us; speedup vs baseline: 1.9986x; 1.0074x over previous
//
#include <hip/hip_runtime.h>

typedef unsigned short u16;
typedef __attribute__((ext_vector_type(8))) short bf16x8;
typedef __attribute__((ext_vector_type(8))) _Float16 f16x8;
typedef __attribute__((ext_vector_type(4))) float f32x4;

#define MFMA16(a, b, c) __builtin_amdgcn_mfma_f32_16x16x32_bf16((a), (b), (c), 0, 0, 0)
#define MFMAH(a, b, c) __builtin_amdgcn_mfma_f32_16x16x32_f16((a), (b), (c), 0, 0, 0)

__device__ __forceinline__ u16 f2bf(float f) {
  unsigned u = __float_as_uint(f);
  return (u16)((u + 0x7FFFu + ((u >> 16) & 1u)) >> 16);
}
__device__ __forceinline__ float bf2f(u16 h) { return __uint_as_float(((unsigned)h) << 16); }
// packed f32x2 -> bf16x2 (RNE), lo word = a, hi word = b
__device__ __forceinline__ unsigned cvt_pk(float a, float b) {
  unsigned r;
  asm("v_cvt_pk_bf16_f32 %0, %1, %2" : "=v"(r) : "v"(a), "v"(b));
  return r;
}
__device__ __forceinline__ u16 f2h(float f) {
  _Float16 h = (_Float16)f;  // v_cvt_f16_f32, RNE
  return __builtin_bit_cast(u16, h);
}
__device__ __forceinline__ unsigned pk_h(float a, float b) {
  return (unsigned)f2h(a) | ((unsigned)f2h(b) << 16);
}

// ---------------- elementwise split: fp32 -> bf16 hi + bf16 lo ----------------
__global__ void split_kernel(const float* __restrict__ in, u16* __restrict__ hi,
                             u16* __restrict__ lo, long n4) {
  long stride = (long)gridDim.x * blockDim.x;
  for (long i = (long)blockIdx.x * blockDim.x + threadIdx.x; i < n4; i += stride) {
    float4 v = ((const float4*)in)[i];
    ushort4 h, l;
    h.x = f2bf(v.x); l.x = f2bf(v.x - bf2f(h.x));
    h.y = f2bf(v.y); l.y = f2bf(v.y - bf2f(h.y));
    h.z = f2bf(v.z); l.z = f2bf(v.z - bf2f(h.z));
    h.w = f2bf(v.w); l.w = f2bf(v.w - bf2f(h.w));
    ((ushort4*)hi)[i] = h;
    ((ushort4*)lo)[i] = l;
  }
}

// ---------------- cos/sin table: (b, t-1, i) -> float2(c,s); 16 heads share positions ----------------
__global__ void cs_table_kernel(const int* __restrict__ pos, float2* __restrict__ cst) {
  int idx = blockIdx.x * 256 + threadIdx.x;  // exactly B*2048*32 threads
  int i = idx & 31;
  int r = idx >> 5;
  int ti = r & 2047;
  int b = r >> 11;
  int p = pos[b * 2048 + ti];
  // replicate reference fp32 rounding of freq and angle, then exact trig
  float fr = (float)pow(10000.0, -(double)i / 32.0);
  float angf = (float)p * fr;
  double sd, cd;
  sincos((double)angf, &sd, &cd);
  cst[idx] = make_float2((float)cd, (float)sd);
}

// ---------------- K pad rows [N, NP): zero (f16 single) ----------------
__global__ void kpad_kernel(u16* __restrict__ kh, int N, int NP) {
  const int per_bh = (NP - N) * 32;  // u32 words per bh
  int idx = blockIdx.x * 256 + threadIdx.x;
  if (idx >= 64 * per_bh) return;
  int bh = idx / per_bh, r = idx - bh * per_bh;
  size_t u = (((size_t)bh * NP + N) * 64 >> 1) + r;
  ((unsigned*)kh)[u] = 0;
}

// ---------------- V transpose: f16 [bh][N][64] -> [bh][64][NP], zero-padded ----------------
__global__ __launch_bounds__(256) void vtransT_kernel(const u16* __restrict__ vb_,
                                                      u16* __restrict__ ot, int N, int NP) {
  __shared__ u16 tile[64][72];
  const int bh = blockIdx.y;
  const int t0 = blockIdx.x * 64;
  const u16* ih = vb_ + (size_t)bh * N * 64;
#pragma unroll
  for (int p = 0; p < 4; ++p) {
    int idx = p * 256 + threadIdx.x;  // 1024 chunks of 4 u16
    int tloc = idx >> 4, c = (idx & 15) * 4;
    int t = t0 + tloc;
    ushort4 a = make_ushort4(0, 0, 0, 0);
    if (t < N) a = *(const ushort4*)(ih + (size_t)t * 64 + c);
    *(ushort4*)&tile[tloc][c] = a;
  }
  __syncthreads();
  u16* oh = ot + (size_t)bh * 64 * NP;
#pragma unroll
  for (int p = 0; p < 4; ++p) {
    int idx = p * 256 + threadIdx.x;  // d (64) x tquad (16)
    int d = idx >> 4, tq = (idx & 15) * 4;
    int t = t0 + tq;
    if (t < NP) {
      ushort4 a;
      a.x = tile[tq + 0][d]; a.y = tile[tq + 1][d];
      a.z = tile[tq + 2][d]; a.w = tile[tq + 3][d];
      *(ushort4*)(oh + (size_t)d * NP + t) = a;
    }
  }
}

// ---------------- bf16x3 emulated-fp32 GEMM: C = A(MxK) * W(NxK)^T + bias ----------------
// EPI 0: fused RoPE (table) + f16 q/k/v outputs (q scaled; k padded layout; v row-major).
// EPI 1: fp32 row-major out.
__device__ __forceinline__ void stage_tile(const u16* __restrict__ g, u16* l,
                                           int row0, int rmax, int K, int k0, int tid) {
#pragma unroll
  for (int t = 0; t < 2; ++t) {
    int c = t * 256 + tid;
    int row = c >> 2, kc = (c & 3) << 3;
    int gr = row0 + row;
    if (gr > rmax) gr = rmax;
    const u16* gp = g + (size_t)gr * K + (k0 + kc);
    __builtin_amdgcn_global_load_lds((const __attribute__((address_space(1))) void*)gp,
                                     (__attribute__((address_space(3))) void*)(l + c * 8),
                                     16, 0, 0);
  }
}

template <int EPI>
__global__ __launch_bounds__(256) void gemm_bf16x3(
    const u16* __restrict__ Ah, const u16* __restrict__ Al,
    const u16* __restrict__ Bh, const u16* __restrict__ Bl,
    const float* __restrict__ bias, const float2* __restrict__ cst,
    float* __restrict__ outf,
    u16* __restrict__ oq, u16* __restrict__ ok, u16* __restrict__ ov,
    int M, int Nn, int K, int Ntok, int NP) {
  __shared__ u16 lAh[4096], lAl[4096], lBh[4096], lBl[4096];
  const int tid = threadIdx.x;
  const int wid = tid >> 6, lane = tid & 63;
  const int wm = wid >> 1, wn = wid & 1;
  const int lg = lane >> 4, lm = lane & 15;
  const int mbase = blockIdx.y * 128, nbase = blockIdx.x * 128;

  f32x4 acc[4][4];
  const f32x4 zero = {0.f, 0.f, 0.f, 0.f};
#pragma unroll
  for (int a = 0; a < 4; ++a)
#pragma unroll
    for (int b = 0; b < 4; ++b) acc[a][b] = zero;

  for (int k0 = 0; k0 < K; k0 += 32) {
    stage_tile(Ah, lAh, mbase, M - 1, K, k0, tid);
    stage_tile(Al, lAl, mbase, M - 1, K, k0, tid);
    stage_tile(Bh, lBh, nbase, Nn - 1, K, k0, tid);
    stage_tile(Bl, lBl, nbase, Nn - 1, K, k0, tid);
    __syncthreads();
    bf16x8 afh[4], afl[4], bfh[4], bfl[4];
#pragma unroll
    for (int f = 0; f < 4; ++f) {
      afh[f] = *(const bf16x8*)&lAh[(wm * 64 + f * 16 + lm) * 32 + lg * 8];
      afl[f] = *(const bf16x8*)&lAl[(wm * 64 + f * 16 + lm) * 32 + lg * 8];
      bfh[f] = *(const bf16x8*)&lBh[(wn * 64 + f * 16 + lm) * 32 + lg * 8];
      bfl[f] = *(const bf16x8*)&lBl[(wn * 64 + f * 16 + lm) * 32 + lg * 8];
    }
#pragma unroll
    for (int fm = 0; fm < 4; ++fm)
#pragma unroll
      for (int fn = 0; fn < 4; ++fn) {
        acc[fm][fn] = MFMA16(afh[fm], bfh[fn], acc[fm][fn]);
        acc[fm][fn] = MFMA16(afh[fm], bfl[fn], acc[fm][fn]);
        acc[fm][fn] = MFMA16(afl[fm], bfh[fn], acc[fm][fn]);
      }
    __syncthreads();
  }

  const int which = (EPI == 0) ? (nbase >> 10) : 1;
  const bool odd = (lm & 1);

#pragma unroll
  for (int fm = 0; fm < 4; ++fm)
#pragma unroll
    for (int fn = 0; fn < 4; ++fn) {
      int col = nbase + wn * 64 + fn * 16 + lm;
      float bv = bias[col];
      int h2 = (col >> 6) & 15, d2 = col & 63;
#pragma unroll
      for (int i = 0; i < 4; ++i) {
        int row = mbase + wm * 64 + fm * 16 + lg * 4 + i;
        float v = acc[fm][fn][i] + bv;
        float partner = __shfl_xor(v, 1);  // neighbor column (re<->im), uniform exec
        if (row < M) {
          if (EPI == 1) {
            outf[(size_t)row * Nn + col] = v;
          } else {
            int b2 = row / Ntok, t2 = row - b2 * Ntok;
            int bh2 = b2 * 16 + h2;
            if (which == 2) {  // v: f16 single, row-major
              ov[((size_t)bh2 * Ntok + t2) * 64 + d2] = f2h(v);
            } else {
              // rope: even lane = re, odd lane = im
              float out = v;
              if (t2 > 0) {
                float2 cs = cst[((size_t)(b2 << 11) + (t2 - 1)) * 32 + (d2 >> 1)];
                out = v * cs.x + (odd ? partner * cs.y : -partner * cs.y);
              }
              if (which == 0) {  // q: fold softmax scale & exp2 conversion, f16 single
                out *= 0.18033688011112042f;  // 0.125 * log2(e)
                oq[((size_t)bh2 * Ntok + t2) * 64 + d2] = f2h(out);
              } else {  // k: f16 single, padded row allocation [bh][NP][64]
                ok[((size_t)bh2 * NP + t2) * 64 + d2] = f2h(out);
              }
            }
          }
        }
      }
    }
}

// ---------------- flash attention v4: f16 single-MFMA core, LDS-shared K/V, 2-phase ----------------
// K tile LDS: chunk (dk*4+lg)*32 + key -> K[key][(dk*4+lg)*8..+8]  (4KB)
// V tile LDS: chunk lg*64 + d        -> V^T[d][kv+lg*8..+8]       (4KB)
template <bool DO_STAGE, bool TAIL>
__device__ __forceinline__ void attn_tile(
    int kv0, int kvn,
    const u16* Kc, const u16* Vc, u16* Kn, u16* Vn,
    const u16* kgb, const u16* vgb,
    int tid, int lg, int lm, int klo, int vlo,
    const f16x8 (&qf16)[2][2],
    float (&m_)[2], float (&l_)[2], f32x4 (&oacc)[2][4],
    unsigned (*pexw)[4], int N) {
  if (DO_STAGE) {  // stage NEXT tile (other buffer); latency hides under this tile's compute
    __builtin_amdgcn_global_load_lds(
        (const __attribute__((address_space(1))) void*)(kgb + (size_t)kvn * 64),
        (__attribute__((address_space(3))) void*)(Kn + tid * 8), 16, 0, 0);
    __builtin_amdgcn_global_load_lds(
        (const __attribute__((address_space(1))) void*)(vgb + kvn),
        (__attribute__((address_space(3))) void*)(Vn + tid * 8), 16, 0, 0);
  }

  const f32x4 zero = {0.f, 0.f, 0.f, 0.f};
  f32x4 s[2][2];
  s[0][0] = zero; s[0][1] = zero; s[1][0] = zero; s[1][1] = zero;
#pragma unroll
  for (int dk = 0; dk < 2; ++dk) {
    f16x8 k0 = *(const f16x8*)&Kc[klo + dk * 1024];
    f16x8 k1 = *(const f16x8*)&Kc[klo + dk * 1024 + 128];
#pragma unroll
    for (int qf = 0; qf < 2; ++qf) {
      s[qf][0] = MFMAH(k0, qf16[qf][dk], s[qf][0]);
      s[qf][1] = MFMAH(k1, qf16[qf][dk], s[qf][1]);
    }
  }
  if (TAIL) {
#pragma unroll
    for (int qf = 0; qf < 2; ++qf)
#pragma unroll
      for (int cf = 0; cf < 2; ++cf)
#pragma unroll
        for (int i = 0; i < 4; ++i)
          if (kv0 + cf * 16 + lg * 4 + i >= N) s[qf][cf][i] = -1e30f;
  }

  bf16x8 pb[2];  // bit container; holds f16x8 pattern
  const int ga = (lg & 1) * 2, gb = ga + 1;
  const int cfs2 = (lg >> 1) * 2;
#pragma unroll
  for (int qf = 0; qf < 2; ++qf) {
    float mx = fmaxf(fmaxf(fmaxf(s[qf][0][0], s[qf][0][1]), fmaxf(s[qf][0][2], s[qf][0][3])),
                     fmaxf(fmaxf(s[qf][1][0], s[qf][1][1]), fmaxf(s[qf][1][2], s[qf][1][3])));
    mx = fmaxf(mx, __shfl_xor(mx, 16));
    mx = fmaxf(mx, __shfl_xor(mx, 32));
    float mr = m_[qf];
    bool nore = __all(mx - mr <= 8.f) != 0;  // defer-max, THR=8 in log2 domain
    float mnew = nore ? mr : fmaxf(mr, mx);
    float p[8];
#pragma unroll
    for (int cf = 0; cf < 2; ++cf)
#pragma unroll
      for (int i = 0; i < 4; ++i)
        p[cf * 4 + i] = __builtin_amdgcn_exp2f(s[qf][cf][i] - mnew);
    float ps = ((p[0] + p[1]) + (p[2] + p[3])) + ((p[4] + p[5]) + (p[6] + p[7]));
    ps += __shfl_xor(ps, 16);
    ps += __shfl_xor(ps, 32);
    if (nore) {
      l_[qf] += ps;
    } else {
      float sc = __builtin_amdgcn_exp2f(mr - mnew);
      l_[qf] = l_[qf] * sc + ps;
      m_[qf] = mnew;
#pragma unroll
      for (int c = 0; c < 4; ++c)
#pragma unroll
        for (int i = 0; i < 4; ++i) oacc[qf][c][i] *= sc;
    }
    // pack P -> f16, redistribute to B-frag via wave-private LDS (DS ops in-order per wave)
    uint4 uw;
    uw.x = pk_h(p[0], p[1]);
    uw.y = pk_h(p[2], p[3]);
    uw.z = pk_h(p[4], p[5]);
    uw.w = pk_h(p[6], p[7]);
    *(uint4*)&pexw[lg * 16 + lm][0] = uw;
    uint2 r0 = *(const uint2*)&pexw[ga * 16 + lm][cfs2];
    uint2 r1 = *(const uint2*)&pexw[gb * 16 + lm][cfs2];
    uint4 pu = make_uint4(r0.x, r0.y, r1.x, r1.y);
    pb[qf] = __builtin_bit_cast(bf16x8, pu);
  }

#pragma unroll
  for (int c = 0; c < 4; ++c) {
    f16x8 vh = *(const f16x8*)&Vc[vlo + c * 128];
    oacc[0][c] = MFMAH(vh, __builtin_bit_cast(f16x8, pb[0]), oacc[0][c]);
    oacc[1][c] = MFMAH(vh, __builtin_bit_cast(f16x8, pb[1]), oacc[1][c]);
  }
}

__global__ __launch_bounds__(256, 6) void attn_kernel(
    const u16* __restrict__ qh, const u16* __restrict__ kh, const u16* __restrict__ vth,
    u16* __restrict__ outh, u16* __restrict__ outl, int N, int NP) {
  __shared__ u16 K0[2048], V0[2048], K1[2048], V1[2048];
  __shared__ unsigned pexm[4][64][4];

  const int id = blockIdx.x;
  const int swz = (id & 7) * 136 + (id >> 3);  // XCD-bijective (1088 = 8*136)
  const int qblk = swz % 17;
  const int bh = swz / 17;
  const int b = bh >> 4, h = bh & 15;
  const int tid = threadIdx.x;
  const int wid = tid >> 6, lane = tid & 63;
  const int lg = lane >> 4, lm = lane & 15;
  const int qbase = qblk * 128 + wid * 32;
  const size_t qoff = (size_t)bh * N * 64;
  const size_t koff = (size_t)bh * NP * 64;
  const size_t voff = (size_t)bh * 64 * NP;

  const int rK = tid >> 5, jK = tid & 31;
  const int lgV = tid >> 6, dV = tid & 63;
  const u16* kgb = kh + koff + (size_t)jK * 64 + rK * 8;
  const u16* vgb = vth + voff + (size_t)dV * NP + lgV * 8;
  const int klo = lg * 256 + lm * 8;  // + dk*1024 + cf*128
  const int vlo = lg * 512 + lm * 8;  // + c*128

  f16x8 qf16[2][2];
#pragma unroll
  for (int qf = 0; qf < 2; ++qf) {
    int qr = qbase + qf * 16 + lm;
    if (qr > N - 1) qr = N - 1;
    const u16* qp = qh + qoff + (size_t)qr * 64 + lg * 8;
    qf16[qf][0] = *(const f16x8*)(qp);
    qf16[qf][1] = *(const f16x8*)(qp + 32);
  }

  const f32x4 zero = {0.f, 0.f, 0.f, 0.f};
  f32x4 oacc[2][4];
#pragma unroll
  for (int qf = 0; qf < 2; ++qf)
#pragma unroll
    for (int c = 0; c < 4; ++c) oacc[qf][c] = zero;
  float m_[2] = {-1e30f, -1e30f}, l_[2] = {0.f, 0.f};
  unsigned(*pexw)[4] = &pexm[wid][0];

  __builtin_amdgcn_global_load_lds(
      (const __attribute__((address_space(1))) void*)kgb,
      (__attribute__((address_space(3))) void*)(K0 + tid * 8), 16, 0, 0);
  __builtin_amdgcn_global_load_lds(
      (const __attribute__((address_space(1))) void*)vgb,
      (__attribute__((address_space(3))) void*)(V0 + tid * 8), 16, 0, 0);
  asm volatile("s_waitcnt vmcnt(0)" ::: "memory");
  __builtin_amdgcn_s_barrier();

  for (int t = 0; t + 2 < 65; t += 2) {
    attn_tile<true, false>(t * 32, (t + 1) * 32, K0, V0, K1, V1, kgb, vgb,
                           tid, lg, lm, klo, vlo, qf16, m_, l_, oacc, pexw, N);
    asm volatile("s_waitcnt vmcnt(0)" ::: "memory");
    __builtin_amdgcn_s_barrier();
    attn_tile<true, false>((t + 1) * 32, (t + 2) * 32, K1, V1, K0, V0, kgb, vgb,
                           tid, lg, lm, klo, vlo, qf16, m_, l_, oacc, pexw, N);
    asm volatile("s_waitcnt vmcnt(0)" ::: "memory");
    __builtin_amdgcn_s_barrier();
  }
  attn_tile<false, true>(64 * 32, 0, K0, V0, K1, V1, kgb, vgb,
                         tid, lg, lm, klo, vlo, qf16, m_, l_, oacc, pexw, N);

  // epilogue: O/l -> bf16 hi/lo (feeds final bf16x3 GEMM)
#pragma unroll
  for (int qf = 0; qf < 2; ++qf) {
    int t = qbase + qf * 16 + lm;
    if (t < N) {
      float rl = 1.f / l_[qf];
      size_t rowoff = ((size_t)(b * N + t)) * 1024 + h * 64 + lg * 4;
#pragma unroll
      for (int c = 0; c < 4; ++c) {
        float v0 = oacc[qf][c][0] * rl, v1 = oacc[qf][c][1] * rl;
        float v2 = oacc[qf][c][2] * rl, v3 = oacc[qf][c][3] * rl;
        unsigned h01 = cvt_pk(v0, v1), h23 = cvt_pk(v2, v3);
        unsigned l01 = cvt_pk(v0 - __uint_as_float(h01 << 16),
                              v1 - __uint_as_float(h01 & 0xffff0000u));
        unsigned l23 = cvt_pk(v2 - __uint_as_float(h23 << 16),
                              v3 - __uint_as_float(h23 & 0xffff0000u));
        *(uint2*)(outh + rowoff + c * 16) = make_uint2(h01, h23);
        *(uint2*)(outl + rowoff + c * 16) = make_uint2(l01, l23);
      }
    }
  }
}

// ---------------- orchestration ----------------
extern "C" void kernel_launch(void* const* d_in, const int* in_sizes, int n_in,
                              void* d_out, int out_size, void* d_ws, size_t ws_size,
                              hipStream_t stream) {
  const float* x     = (const float*)d_in[0];
  const int*   pos   = (const int*)  d_in[1];
  const float* w_qkv = (const float*)d_in[2];
  const float* b_qkv = (const float*)d_in[3];
  const float* w_fc  = (const float*)d_in[4];
  const float* b_fc  = (const float*)d_in[5];
  (void)in_sizes; (void)n_in; (void)out_size; (void)ws_size;

  const int B = 4, N = 2049, NP = 2080;
  const long EL = (long)B * N * 1024;       // 8,392,704
  const long ELP = (long)B * 16 * NP * 64;  // padded K elems

  char* base = (char*)d_ws;
  size_t off = 0;
  auto alloc = [&](size_t bytes) -> void* {
    void* p = base + off;
    off += (bytes + 255) & ~(size_t)255;
    return p;
  };
  u16* qhh = (u16*)alloc(EL * 2);                      // q f16 (scaled)
  u16* khh = (u16*)alloc(ELP * 2);                     // k f16 (padded)
  u16* vbh = (u16*)alloc(EL * 2);                      // v f16 row-major
  u16* vth = (u16*)alloc((size_t)64 * 64 * NP * 2);    // v^T f16 padded
  u16* xh  = (u16*)alloc(EL * 2);                      // x / attn-out bf16 hi
  u16* xl  = (u16*)alloc(EL * 2);                      // x / attn-out bf16 lo
  u16* wqh = (u16*)alloc((size_t)3072 * 1024 * 2);
  u16* wql = (u16*)alloc((size_t)3072 * 1024 * 2);
  u16* wfh = (u16*)alloc((size_t)1024 * 1024 * 2);
  u16* wfl = (u16*)alloc((size_t)1024 * 1024 * 2);
  float2* cst = (float2*)alloc((size_t)B * 2048 * 32 * 8);

  // 1. split inputs; build cos/sin table (one fp64 sincos per (b,t,i), shared by 16 heads)
  split_kernel<<<2048, 256, 0, stream>>>(x, xh, xl, EL / 4);
  split_kernel<<<1024, 256, 0, stream>>>(w_qkv, wqh, wql, (long)3072 * 1024 / 4);
  split_kernel<<<512, 256, 0, stream>>>(w_fc, wfh, wfl, (long)1024 * 1024 / 4);
  cs_table_kernel<<<(B * 2048 * 32) / 256, 256, 0, stream>>>(pos, cst);
  // 2. fused QKV projection with fused RoPE + f16 q/k/v epilogue
  gemm_bf16x3<0><<<dim3(24, 65), 256, 0, stream>>>(xh, xl, wqh, wql, b_qkv, cst, nullptr,
                                                   qhh, khh, vbh, 8196, 3072, 1024, N, NP);
  // 3. pad K rows [N,NP); transpose+pad V (f16 -> [bh][64][NP])
  kpad_kernel<<<(64 * (NP - N) * 32 + 255) / 256, 256, 0, stream>>>(khh, N, NP);
  vtransT_kernel<<<dim3((NP + 63) / 64, 64), 256, 0, stream>>>(vbh, vth, N, NP);
  // 4. flash attention (f16 core) -> bf16 hi/lo (B,N,D), reusing xh/xl
  attn_kernel<<<dim3(1088), 256, 0, stream>>>(qhh, khh, vth, xh, xl, N, NP);
  // 5. output projection -> d_out
  gemm_bf16x3<1><<<dim3(8, 65), 256, 0, stream>>>(xh, xl, wfh, wfl, b_fc, nullptr,
                                                  (float*)d_out, nullptr, nullptr, nullptr,
                                                  8196, 1024, 1024, N, NP);
}

// Round 6
// 491.530 us; speedup vs baseline: 2.7115x; 1.3567x over previous
//
#include <hip/hip_runtime.h>

typedef unsigned short u16;
typedef __attribute__((ext_vector_type(8))) short bf16x8;
typedef __attribute__((ext_vector_type(8))) _Float16 f16x8;
typedef __attribute__((ext_vector_type(4))) float f32x4;

#define MFMA16(a, b, c) __builtin_amdgcn_mfma_f32_16x16x32_bf16((a), (b), (c), 0, 0, 0)
#define MFMAH(a, b, c) __builtin_amdgcn_mfma_f32_16x16x32_f16((a), (b), (c), 0, 0, 0)

__device__ __forceinline__ u16 f2bf(float f) {
  unsigned u = __float_as_uint(f);
  return (u16)((u + 0x7FFFu + ((u >> 16) & 1u)) >> 16);
}
__device__ __forceinline__ float bf2f(u16 h) { return __uint_as_float(((unsigned)h) << 16); }
// packed f32x2 -> bf16x2 (RNE), lo word = a, hi word = b
__device__ __forceinline__ unsigned cvt_pk(float a, float b) {
  unsigned r;
  asm("v_cvt_pk_bf16_f32 %0, %1, %2" : "=v"(r) : "v"(a), "v"(b));
  return r;
}
__device__ __forceinline__ u16 f2h(float f) {
  _Float16 h = (_Float16)f;  // v_cvt_f16_f32, RNE
  return __builtin_bit_cast(u16, h);
}
__device__ __forceinline__ unsigned pk_h(float a, float b) {
  return (unsigned)f2h(a) | ((unsigned)f2h(b) << 16);
}

// ---------------- elementwise split: fp32 -> bf16 hi + bf16 lo ----------------
__global__ void split_kernel(const float* __restrict__ in, u16* __restrict__ hi,
                             u16* __restrict__ lo, long n4) {
  long stride = (long)gridDim.x * blockDim.x;
  for (long i = (long)blockIdx.x * blockDim.x + threadIdx.x; i < n4; i += stride) {
    float4 v = ((const float4*)in)[i];
    ushort4 h, l;
    h.x = f2bf(v.x); l.x = f2bf(v.x - bf2f(h.x));
    h.y = f2bf(v.y); l.y = f2bf(v.y - bf2f(h.y));
    h.z = f2bf(v.z); l.z = f2bf(v.z - bf2f(h.z));
    h.w = f2bf(v.w); l.w = f2bf(v.w - bf2f(h.w));
    ((ushort4*)hi)[i] = h;
    ((ushort4*)lo)[i] = l;
  }
}

// ---------------- cos/sin table: (b, t-1, i) -> float2(c,s); 16 heads share positions ----------------
__global__ void cs_table_kernel(const int* __restrict__ pos, float2* __restrict__ cst) {
  int idx = blockIdx.x * 256 + threadIdx.x;  // exactly B*2048*32 threads
  int i = idx & 31;
  int r = idx >> 5;
  int ti = r & 2047;
  int b = r >> 11;
  int p = pos[b * 2048 + ti];
  // replicate reference fp32 rounding of freq and angle, then exact trig
  float fr = (float)pow(10000.0, -(double)i / 32.0);
  float angf = (float)p * fr;
  double sd, cd;
  sincos((double)angf, &sd, &cd);
  cst[idx] = make_float2((float)cd, (float)sd);
}

// ---------------- K pad rows [N, NP): zero (f16 single) ----------------
__global__ void kpad_kernel(u16* __restrict__ kh, int N, int NP) {
  const int per_bh = (NP - N) * 32;  // u32 words per bh
  int idx = blockIdx.x * 256 + threadIdx.x;
  if (idx >= 64 * per_bh) return;
  int bh = idx / per_bh, r = idx - bh * per_bh;
  size_t u = (((size_t)bh * NP + N) * 64 >> 1) + r;
  ((unsigned*)kh)[u] = 0;
}

// ---------------- V transpose: f16 [bh][N][64] -> [bh][64][NP], zero-padded ----------------
__global__ __launch_bounds__(256) void vtransT_kernel(const u16* __restrict__ vb_,
                                                      u16* __restrict__ ot, int N, int NP) {
  __shared__ u16 tile[64][72];
  const int bh = blockIdx.y;
  const int t0 = blockIdx.x * 64;
  const u16* ih = vb_ + (size_t)bh * N * 64;
#pragma unroll
  for (int p = 0; p < 4; ++p) {
    int idx = p * 256 + threadIdx.x;  // 1024 chunks of 4 u16
    int tloc = idx >> 4, c = (idx & 15) * 4;
    int t = t0 + tloc;
    ushort4 a = make_ushort4(0, 0, 0, 0);
    if (t < N) a = *(const ushort4*)(ih + (size_t)t * 64 + c);
    *(ushort4*)&tile[tloc][c] = a;
  }
  __syncthreads();
  u16* oh = ot + (size_t)bh * 64 * NP;
#pragma unroll
  for (int p = 0; p < 4; ++p) {
    int idx = p * 256 + threadIdx.x;  // d (64) x tquad (16)
    int d = idx >> 4, tq = (idx & 15) * 4;
    int t = t0 + tq;
    if (t < NP) {
      ushort4 a;
      a.x = tile[tq + 0][d]; a.y = tile[tq + 1][d];
      a.z = tile[tq + 2][d]; a.w = tile[tq + 3][d];
      *(ushort4*)(oh + (size_t)d * NP + t) = a;
    }
  }
}

// ---------------- bf16x3 emulated-fp32 GEMM: C = A(MxK) * W(NxK)^T + bias ----------------
// EPI 0: fused RoPE (table) + f16 q/k/v outputs (q scaled; k padded layout; v row-major).
// EPI 1: fp32 row-major out.
__device__ __forceinline__ void stage_tile(const u16* __restrict__ g, u16* l,
                                           int row0, int rmax, int K, int k0, int tid) {
#pragma unroll
  for (int t = 0; t < 2; ++t) {
    int c = t * 256 + tid;
    int row = c >> 2, kc = (c & 3) << 3;
    int gr = row0 + row;
    if (gr > rmax) gr = rmax;
    const u16* gp = g + (size_t)gr * K + (k0 + kc);
    __builtin_amdgcn_global_load_lds((const __attribute__((address_space(1))) void*)gp,
                                     (__attribute__((address_space(3))) void*)(l + c * 8),
                                     16, 0, 0);
  }
}

template <int EPI>
__global__ __launch_bounds__(256) void gemm_bf16x3(
    const u16* __restrict__ Ah, const u16* __restrict__ Al,
    const u16* __restrict__ Bh, const u16* __restrict__ Bl,
    const float* __restrict__ bias, const float2* __restrict__ cst,
    float* __restrict__ outf,
    u16* __restrict__ oq, u16* __restrict__ ok, u16* __restrict__ ov,
    int M, int Nn, int K, int Ntok, int NP) {
  __shared__ u16 lAh[4096], lAl[4096], lBh[4096], lBl[4096];
  const int tid = threadIdx.x;
  const int wid = tid >> 6, lane = tid & 63;
  const int wm = wid >> 1, wn = wid & 1;
  const int lg = lane >> 4, lm = lane & 15;
  const int mbase = blockIdx.y * 128, nbase = blockIdx.x * 128;

  f32x4 acc[4][4];
  const f32x4 zero = {0.f, 0.f, 0.f, 0.f};
#pragma unroll
  for (int a = 0; a < 4; ++a)
#pragma unroll
    for (int b = 0; b < 4; ++b) acc[a][b] = zero;

  for (int k0 = 0; k0 < K; k0 += 32) {
    stage_tile(Ah, lAh, mbase, M - 1, K, k0, tid);
    stage_tile(Al, lAl, mbase, M - 1, K, k0, tid);
    stage_tile(Bh, lBh, nbase, Nn - 1, K, k0, tid);
    stage_tile(Bl, lBl, nbase, Nn - 1, K, k0, tid);
    __syncthreads();
    bf16x8 afh[4], afl[4], bfh[4], bfl[4];
#pragma unroll
    for (int f = 0; f < 4; ++f) {
      afh[f] = *(const bf16x8*)&lAh[(wm * 64 + f * 16 + lm) * 32 + lg * 8];
      afl[f] = *(const bf16x8*)&lAl[(wm * 64 + f * 16 + lm) * 32 + lg * 8];
      bfh[f] = *(const bf16x8*)&lBh[(wn * 64 + f * 16 + lm) * 32 + lg * 8];
      bfl[f] = *(const bf16x8*)&lBl[(wn * 64 + f * 16 + lm) * 32 + lg * 8];
    }
#pragma unroll
    for (int fm = 0; fm < 4; ++fm)
#pragma unroll
      for (int fn = 0; fn < 4; ++fn) {
        acc[fm][fn] = MFMA16(afh[fm], bfh[fn], acc[fm][fn]);
        acc[fm][fn] = MFMA16(afh[fm], bfl[fn], acc[fm][fn]);
        acc[fm][fn] = MFMA16(afl[fm], bfh[fn], acc[fm][fn]);
      }
    __syncthreads();
  }

  const int which = (EPI == 0) ? (nbase >> 10) : 1;
  const bool odd = (lm & 1);

#pragma unroll
  for (int fm = 0; fm < 4; ++fm)
#pragma unroll
    for (int fn = 0; fn < 4; ++fn) {
      int col = nbase + wn * 64 + fn * 16 + lm;
      float bv = bias[col];
      int h2 = (col >> 6) & 15, d2 = col & 63;
#pragma unroll
      for (int i = 0; i < 4; ++i) {
        int row = mbase + wm * 64 + fm * 16 + lg * 4 + i;
        float v = acc[fm][fn][i] + bv;
        float partner = __shfl_xor(v, 1);  // neighbor column (re<->im), uniform exec
        if (row < M) {
          if (EPI == 1) {
            outf[(size_t)row * Nn + col] = v;
          } else {
            int b2 = row / Ntok, t2 = row - b2 * Ntok;
            int bh2 = b2 * 16 + h2;
            if (which == 2) {  // v: f16 single, row-major
              ov[((size_t)bh2 * Ntok + t2) * 64 + d2] = f2h(v);
            } else {
              // rope: even lane = re, odd lane = im
              float out = v;
              if (t2 > 0) {
                float2 cs = cst[((size_t)(b2 << 11) + (t2 - 1)) * 32 + (d2 >> 1)];
                out = v * cs.x + (odd ? partner * cs.y : -partner * cs.y);
              }
              if (which == 0) {  // q: fold softmax scale & exp2 conversion, f16 single
                out *= 0.18033688011112042f;  // 0.125 * log2(e)
                oq[((size_t)bh2 * Ntok + t2) * 64 + d2] = f2h(out);
              } else {  // k: f16 single, padded row allocation [bh][NP][64]
                ok[((size_t)bh2 * NP + t2) * 64 + d2] = f2h(out);
              }
            }
          }
        }
      }
    }
}

// ---------------- flash attention v5: 8-wave blocks, 256 q-rows, KVBLK=64, 2-phase ----------------
// K tile LDS (8KB): chunk rK*64+key -> K[key][rK*8..+8]  (rK = d-octet 0..7)
// V tile LDS (8KB): chunk kr*64+d   -> V^T[d][kv+kr*8..+8] (kr = key-octet 0..7)
template <bool DO_STAGE, bool TAIL>
__device__ __forceinline__ void attn_tile(
    int kv0, int kvn,
    const u16* Kc, const u16* Vc, u16* Kn, u16* Vn,
    const u16* kgb, const u16* vgb,
    int tid, int lg, int lm, int kvbase,
    const f16x8 (&qf16)[2][2],
    float (&m_)[2], float (&l_)[2], f32x4 (&oacc)[2][4],
    unsigned (*pexw)[4], int N) {
  if (DO_STAGE) {  // stage NEXT tile (other buffer); latency hides under this tile's compute
    __builtin_amdgcn_global_load_lds(
        (const __attribute__((address_space(1))) void*)(kgb + (size_t)kvn * 64),
        (__attribute__((address_space(3))) void*)(Kn + tid * 8), 16, 0, 0);
    __builtin_amdgcn_global_load_lds(
        (const __attribute__((address_space(1))) void*)(vgb + kvn),
        (__attribute__((address_space(3))) void*)(Vn + tid * 8), 16, 0, 0);
  }

  const f32x4 zero = {0.f, 0.f, 0.f, 0.f};
  f32x4 s[2][4];
#pragma unroll
  for (int qf = 0; qf < 2; ++qf)
#pragma unroll
    for (int cf = 0; cf < 4; ++cf) s[qf][cf] = zero;
#pragma unroll
  for (int cf = 0; cf < 4; ++cf)
#pragma unroll
    for (int dk = 0; dk < 2; ++dk) {
      f16x8 kf = *(const f16x8*)&Kc[kvbase + dk * 2048 + cf * 128];
      s[0][cf] = MFMAH(kf, qf16[0][dk], s[0][cf]);
      s[1][cf] = MFMAH(kf, qf16[1][dk], s[1][cf]);
    }
  if (TAIL) {
#pragma unroll
    for (int qf = 0; qf < 2; ++qf)
#pragma unroll
      for (int cf = 0; cf < 4; ++cf)
#pragma unroll
        for (int i = 0; i < 4; ++i)
          if (kv0 + cf * 16 + lg * 4 + i >= N) s[qf][cf][i] = -1e30f;
  }

  f16x8 pb[2][2];  // [qf][ks]
  const int ga = (lg & 1) * 2, gb = ga + 1;
  const int cfs2 = (lg >> 1) * 2;
#pragma unroll
  for (int qf = 0; qf < 2; ++qf) {
    float mx = s[qf][0][0];
#pragma unroll
    for (int cf = 0; cf < 4; ++cf)
#pragma unroll
      for (int i = 0; i < 4; ++i) mx = fmaxf(mx, s[qf][cf][i]);
    mx = fmaxf(mx, __shfl_xor(mx, 16));
    mx = fmaxf(mx, __shfl_xor(mx, 32));
    float mr = m_[qf];
    bool nore = __all(mx - mr <= 8.f) != 0;  // defer-max, THR=8 in log2 domain
    float mnew = nore ? mr : fmaxf(mr, mx);
    float p[16];
#pragma unroll
    for (int cf = 0; cf < 4; ++cf)
#pragma unroll
      for (int i = 0; i < 4; ++i)
        p[cf * 4 + i] = __builtin_amdgcn_exp2f(s[qf][cf][i] - mnew);
    float ps = 0.f;
#pragma unroll
    for (int j = 0; j < 16; ++j) ps += p[j];
    ps += __shfl_xor(ps, 16);
    ps += __shfl_xor(ps, 32);
    if (nore) {
      l_[qf] += ps;
    } else {
      float sc = __builtin_amdgcn_exp2f(mr - mnew);
      l_[qf] = l_[qf] * sc + ps;
      m_[qf] = mnew;
#pragma unroll
      for (int c = 0; c < 4; ++c)
#pragma unroll
        for (int i = 0; i < 4; ++i) oacc[qf][c][i] *= sc;
    }
    // pack P -> f16, redistribute to B-frag via wave-private LDS (DS in-order per wave)
#pragma unroll
    for (int ks = 0; ks < 2; ++ks) {
      uint4 uw;
      uw.x = pk_h(p[ks * 8 + 0], p[ks * 8 + 1]);
      uw.y = pk_h(p[ks * 8 + 2], p[ks * 8 + 3]);
      uw.z = pk_h(p[ks * 8 + 4], p[ks * 8 + 5]);
      uw.w = pk_h(p[ks * 8 + 6], p[ks * 8 + 7]);
      *(uint4*)&pexw[lg * 16 + lm][0] = uw;
      uint2 r0 = *(const uint2*)&pexw[ga * 16 + lm][cfs2];
      uint2 r1 = *(const uint2*)&pexw[gb * 16 + lm][cfs2];
      uint4 pu = make_uint4(r0.x, r0.y, r1.x, r1.y);
      pb[qf][ks] = __builtin_bit_cast(f16x8, pu);
    }
  }

#pragma unroll
  for (int c = 0; c < 4; ++c)
#pragma unroll
    for (int ks = 0; ks < 2; ++ks) {
      f16x8 vh = *(const f16x8*)&Vc[kvbase + ks * 2048 + c * 128];
      oacc[0][c] = MFMAH(vh, pb[0][ks], oacc[0][c]);
      oacc[1][c] = MFMAH(vh, pb[1][ks], oacc[1][c]);
    }
}

__global__ __launch_bounds__(512, 4) void attn_kernel(
    const u16* __restrict__ qh, const u16* __restrict__ kh, const u16* __restrict__ vth,
    u16* __restrict__ outh, u16* __restrict__ outl, int N, int NP) {
  __shared__ u16 K0[4096], V0[4096], K1[4096], V1[4096];
  __shared__ unsigned pexm[8][64][4];

  const int id = blockIdx.x;
  const int swz = (id & 7) * 72 + (id >> 3);  // XCD-bijective (576 = 8*72)
  const int qblk = swz % 9;
  const int bh = swz / 9;
  const int b = bh >> 4, h = bh & 15;
  const int tid = threadIdx.x;
  const int wid = tid >> 6, lane = tid & 63;
  const int lg = lane >> 4, lm = lane & 15;
  const int qbase = qblk * 256 + wid * 32;
  const size_t qoff = (size_t)bh * N * 64;
  const size_t koff = (size_t)bh * NP * 64;
  const size_t voff = (size_t)bh * 64 * NP;

  // staging sources: K thread t -> row (t&63), d-octet (t>>6); V thread t -> d (t&63), key-octet (t>>6)
  const int jK = tid & 63, rK = tid >> 6;
  const u16* kgb = kh + koff + (size_t)jK * 64 + rK * 8;
  const u16* vgb = vth + voff + (size_t)jK * NP + rK * 8;
  const int kvbase = lg * 512 + lm * 8;  // + dk|ks*2048 + cf|c*128

  f16x8 qf16[2][2];
#pragma unroll
  for (int qf = 0; qf < 2; ++qf) {
    int qr = qbase + qf * 16 + lm;
    if (qr > N - 1) qr = N - 1;
    const u16* qp = qh + qoff + (size_t)qr * 64 + lg * 8;
    qf16[qf][0] = *(const f16x8*)(qp);
    qf16[qf][1] = *(const f16x8*)(qp + 32);
  }

  const f32x4 zero = {0.f, 0.f, 0.f, 0.f};
  f32x4 oacc[2][4];
#pragma unroll
  for (int qf = 0; qf < 2; ++qf)
#pragma unroll
    for (int c = 0; c < 4; ++c) oacc[qf][c] = zero;
  float m_[2] = {-1e30f, -1e30f}, l_[2] = {0.f, 0.f};
  unsigned(*pexw)[4] = &pexm[wid][0];

  // prologue: stage tile 0 into buffer 0
  __builtin_amdgcn_global_load_lds(
      (const __attribute__((address_space(1))) void*)kgb,
      (__attribute__((address_space(3))) void*)(K0 + tid * 8), 16, 0, 0);
  __builtin_amdgcn_global_load_lds(
      (const __attribute__((address_space(1))) void*)vgb,
      (__attribute__((address_space(3))) void*)(V0 + tid * 8), 16, 0, 0);
  asm volatile("s_waitcnt vmcnt(0)" ::: "memory");
  __builtin_amdgcn_s_barrier();

  // tiles 0..31 in pairs (stage t+1 during t), tile 32 = tail (keys 2048..2111, padded)
  for (int t = 0; t < 32; t += 2) {
    attn_tile<true, false>(t * 64, (t + 1) * 64, K0, V0, K1, V1, kgb, vgb,
                           tid, lg, lm, kvbase, qf16, m_, l_, oacc, pexw, N);
    asm volatile("s_waitcnt vmcnt(0)" ::: "memory");
    __builtin_amdgcn_s_barrier();
    attn_tile<true, false>((t + 1) * 64, (t + 2) * 64, K1, V1, K0, V0, kgb, vgb,
                           tid, lg, lm, kvbase, qf16, m_, l_, oacc, pexw, N);
    asm volatile("s_waitcnt vmcnt(0)" ::: "memory");
    __builtin_amdgcn_s_barrier();
  }
  attn_tile<false, true>(32 * 64, 0, K0, V0, K1, V1, kgb, vgb,
                         tid, lg, lm, kvbase, qf16, m_, l_, oacc, pexw, N);

  // epilogue: O/l -> bf16 hi/lo (feeds final bf16x3 GEMM)
#pragma unroll
  for (int qf = 0; qf < 2; ++qf) {
    int t = qbase + qf * 16 + lm;
    if (t < N) {
      float rl = 1.f / l_[qf];
      size_t rowoff = ((size_t)(b * N + t)) * 1024 + h * 64 + lg * 4;
#pragma unroll
      for (int c = 0; c < 4; ++c) {
        float v0 = oacc[qf][c][0] * rl, v1 = oacc[qf][c][1] * rl;
        float v2 = oacc[qf][c][2] * rl, v3 = oacc[qf][c][3] * rl;
        unsigned h01 = cvt_pk(v0, v1), h23 = cvt_pk(v2, v3);
        unsigned l01 = cvt_pk(v0 - __uint_as_float(h01 << 16),
                              v1 - __uint_as_float(h01 & 0xffff0000u));
        unsigned l23 = cvt_pk(v2 - __uint_as_float(h23 << 16),
                              v3 - __uint_as_float(h23 & 0xffff0000u));
        *(uint2*)(outh + rowoff + c * 16) = make_uint2(h01, h23);
        *(uint2*)(outl + rowoff + c * 16) = make_uint2(l01, l23);
      }
    }
  }
}

// ---------------- orchestration ----------------
extern "C" void kernel_launch(void* const* d_in, const int* in_sizes, int n_in,
                              void* d_out, int out_size, void* d_ws, size_t ws_size,
                              hipStream_t stream) {
  const float* x     = (const float*)d_in[0];
  const int*   pos   = (const int*)  d_in[1];
  const float* w_qkv = (const float*)d_in[2];
  const float* b_qkv = (const float*)d_in[3];
  const float* w_fc  = (const float*)d_in[4];
  const float* b_fc  = (const float*)d_in[5];
  (void)in_sizes; (void)n_in; (void)out_size; (void)ws_size;

  const int B = 4, N = 2049, NP = 2112;  // NP = 33*64 (KVBLK=64 tiles)
  const long EL = (long)B * N * 1024;       // 8,392,704
  const long ELP = (long)B * 16 * NP * 64;  // padded K elems

  char* base = (char*)d_ws;
  size_t off = 0;
  auto alloc = [&](size_t bytes) -> void* {
    void* p = base + off;
    off += (bytes + 255) & ~(size_t)255;
    return p;
  };
  u16* qhh = (u16*)alloc(EL * 2);                      // q f16 (scaled)
  u16* khh = (u16*)alloc(ELP * 2);                     // k f16 (padded rows)
  u16* vbh = (u16*)alloc(EL * 2);                      // v f16 row-major
  u16* vth = (u16*)alloc((size_t)64 * 64 * NP * 2);    // v^T f16 padded cols
  u16* xh  = (u16*)alloc(EL * 2);                      // x / attn-out bf16 hi
  u16* xl  = (u16*)alloc(EL * 2);                      // x / attn-out bf16 lo
  u16* wqh = (u16*)alloc((size_t)3072 * 1024 * 2);
  u16* wql = (u16*)alloc((size_t)3072 * 1024 * 2);
  u16* wfh = (u16*)alloc((size_t)1024 * 1024 * 2);
  u16* wfl = (u16*)alloc((size_t)1024 * 1024 * 2);
  float2* cst = (float2*)alloc((size_t)B * 2048 * 32 * 8);

  // 1. split inputs; build cos/sin table (one fp64 sincos per (b,t,i), shared by 16 heads)
  split_kernel<<<2048, 256, 0, stream>>>(x, xh, xl, EL / 4);
  split_kernel<<<1024, 256, 0, stream>>>(w_qkv, wqh, wql, (long)3072 * 1024 / 4);
  split_kernel<<<512, 256, 0, stream>>>(w_fc, wfh, wfl, (long)1024 * 1024 / 4);
  cs_table_kernel<<<(B * 2048 * 32) / 256, 256, 0, stream>>>(pos, cst);
  // 2. fused QKV projection with fused RoPE + f16 q/k/v epilogue
  gemm_bf16x3<0><<<dim3(24, 65), 256, 0, stream>>>(xh, xl, wqh, wql, b_qkv, cst, nullptr,
                                                   qhh, khh, vbh, 8196, 3072, 1024, N, NP);
  // 3. pad K rows [N,NP); transpose+pad V (f16 -> [bh][64][NP])
  kpad_kernel<<<(64 * (NP - N) * 32 + 255) / 256, 256, 0, stream>>>(khh, N, NP);
  vtransT_kernel<<<dim3(NP / 64, 64), 256, 0, stream>>>(vbh, vth, N, NP);
  // 4. flash attention (f16 core, 8-wave/256-row blocks) -> bf16 hi/lo, reusing xh/xl
  attn_kernel<<<dim3(576), 512, 0, stream>>>(qhh, khh, vth, xh, xl, N, NP);
  // 5. output projection -> d_out
  gemm_bf16x3<1><<<dim3(8, 65), 256, 0, stream>>>(xh, xl, wfh, wfl, b_fc, nullptr,
                                                  (float*)d_out, nullptr, nullptr, nullptr,
                                                  8196, 1024, 1024, N, NP);
}

// Round 7
// 490.219 us; speedup vs baseline: 2.7188x; 1.0027x over previous
//
#include <hip/hip_runtime.h>

typedef unsigned short u16;
typedef __attribute__((ext_vector_type(8))) short bf16x8;
typedef __attribute__((ext_vector_type(8))) _Float16 f16x8;
typedef __attribute__((ext_vector_type(4))) float f32x4;

#define MFMA16(a, b, c) __builtin_amdgcn_mfma_f32_16x16x32_bf16((a), (b), (c), 0, 0, 0)
#define MFMAH(a, b, c) __builtin_amdgcn_mfma_f32_16x16x32_f16((a), (b), (c), 0, 0, 0)

__device__ __forceinline__ u16 f2bf(float f) {
  unsigned u = __float_as_uint(f);
  return (u16)((u + 0x7FFFu + ((u >> 16) & 1u)) >> 16);
}
__device__ __forceinline__ float bf2f(u16 h) { return __uint_as_float(((unsigned)h) << 16); }
// packed f32x2 -> bf16x2 (RNE), lo word = a, hi word = b
__device__ __forceinline__ unsigned cvt_pk(float a, float b) {
  unsigned r;
  asm("v_cvt_pk_bf16_f32 %0, %1, %2" : "=v"(r) : "v"(a), "v"(b));
  return r;
}
__device__ __forceinline__ u16 f2h(float f) {
  _Float16 h = (_Float16)f;  // v_cvt_f16_f32, RNE
  return __builtin_bit_cast(u16, h);
}
__device__ __forceinline__ unsigned pk_h(float a, float b) {
  return (unsigned)f2h(a) | ((unsigned)f2h(b) << 16);
}

// ---------------- elementwise split: fp32 -> bf16 hi + bf16 lo ----------------
__global__ void split_kernel(const float* __restrict__ in, u16* __restrict__ hi,
                             u16* __restrict__ lo, long n4) {
  long stride = (long)gridDim.x * blockDim.x;
  for (long i = (long)blockIdx.x * blockDim.x + threadIdx.x; i < n4; i += stride) {
    float4 v = ((const float4*)in)[i];
    ushort4 h, l;
    h.x = f2bf(v.x); l.x = f2bf(v.x - bf2f(h.x));
    h.y = f2bf(v.y); l.y = f2bf(v.y - bf2f(h.y));
    h.z = f2bf(v.z); l.z = f2bf(v.z - bf2f(h.z));
    h.w = f2bf(v.w); l.w = f2bf(v.w - bf2f(h.w));
    ((ushort4*)hi)[i] = h;
    ((ushort4*)lo)[i] = l;
  }
}

// ---------------- cos/sin table: (b, t-1, i) -> float2(c,s); 16 heads share positions ----------------
__global__ void cs_table_kernel(const int* __restrict__ pos, float2* __restrict__ cst) {
  int idx = blockIdx.x * 256 + threadIdx.x;  // exactly B*2048*32 threads
  int i = idx & 31;
  int r = idx >> 5;
  int ti = r & 2047;
  int b = r >> 11;
  int p = pos[b * 2048 + ti];
  // replicate reference fp32 rounding of freq and angle, then exact trig
  float fr = (float)pow(10000.0, -(double)i / 32.0);
  float angf = (float)p * fr;
  double sd, cd;
  sincos((double)angf, &sd, &cd);
  cst[idx] = make_float2((float)cd, (float)sd);
}

// ---------------- K pad rows [N, NP): zero (f16 single) ----------------
__global__ void kpad_kernel(u16* __restrict__ kh, int N, int NP) {
  const int per_bh = (NP - N) * 32;  // u32 words per bh
  int idx = blockIdx.x * 256 + threadIdx.x;
  if (idx >= 64 * per_bh) return;
  int bh = idx / per_bh, r = idx - bh * per_bh;
  size_t u = (((size_t)bh * NP + N) * 64 >> 1) + r;
  ((unsigned*)kh)[u] = 0;
}

// ---------------- V transpose: f16 [bh][N][64] -> [bh][64][NP], zero-padded ----------------
__global__ __launch_bounds__(256) void vtransT_kernel(const u16* __restrict__ vb_,
                                                      u16* __restrict__ ot, int N, int NP) {
  __shared__ u16 tile[64][72];
  const int bh = blockIdx.y;
  const int t0 = blockIdx.x * 64;
  const u16* ih = vb_ + (size_t)bh * N * 64;
#pragma unroll
  for (int p = 0; p < 4; ++p) {
    int idx = p * 256 + threadIdx.x;  // 1024 chunks of 4 u16
    int tloc = idx >> 4, c = (idx & 15) * 4;
    int t = t0 + tloc;
    ushort4 a = make_ushort4(0, 0, 0, 0);
    if (t < N) a = *(const ushort4*)(ih + (size_t)t * 64 + c);
    *(ushort4*)&tile[tloc][c] = a;
  }
  __syncthreads();
  u16* oh = ot + (size_t)bh * 64 * NP;
#pragma unroll
  for (int p = 0; p < 4; ++p) {
    int idx = p * 256 + threadIdx.x;  // d (64) x tquad (16)
    int d = idx >> 4, tq = (idx & 15) * 4;
    int t = t0 + tq;
    if (t < NP) {
      ushort4 a;
      a.x = tile[tq + 0][d]; a.y = tile[tq + 1][d];
      a.z = tile[tq + 2][d]; a.w = tile[tq + 3][d];
      *(ushort4*)(oh + (size_t)d * NP + t) = a;
    }
  }
}

// ---------------- bf16x3 emulated-fp32 GEMM: C = A(MxK) * W(NxK)^T + bias ----------------
// LDS tiles are XOR-swizzled (T2): LDS[row][g'] holds global granule g'^((row>>1)&3)
// (granule = 16B). Writes stay linear for global_load_lds; the SOURCE address is
// pre-swizzled (rule #21) and reads apply the same involution -> identical fragments,
// bank map becomes bijective over the 8 (row&1, granule) slots (2-way residual = free).
__device__ __forceinline__ void stage_tile(const u16* __restrict__ g, u16* l,
                                           int row0, int rmax, int K, int k0, int tid) {
#pragma unroll
  for (int t = 0; t < 2; ++t) {
    int c = t * 256 + tid;
    int row = c >> 2;
    int kc = (((c & 3) ^ ((c >> 3) & 3)) << 3);  // pre-swizzled source granule
    int gr = row0 + row;
    if (gr > rmax) gr = rmax;
    const u16* gp = g + (size_t)gr * K + (k0 + kc);
    __builtin_amdgcn_global_load_lds((const __attribute__((address_space(1))) void*)gp,
                                     (__attribute__((address_space(3))) void*)(l + c * 8),
                                     16, 0, 0);
  }
}
// swizzled fragment offset (u16 units): row R (stride 32 u16), granule lg
__device__ __forceinline__ int swz_off(int R, int lg) {
  return R * 32 + ((lg ^ ((R >> 1) & 3)) << 3);
}

template <int EPI>
__global__ __launch_bounds__(256) void gemm_bf16x3(
    const u16* __restrict__ Ah, const u16* __restrict__ Al,
    const u16* __restrict__ Bh, const u16* __restrict__ Bl,
    const float* __restrict__ bias, const float2* __restrict__ cst,
    float* __restrict__ outf,
    u16* __restrict__ oq, u16* __restrict__ ok, u16* __restrict__ ov,
    int M, int Nn, int K, int Ntok, int NP) {
  __shared__ u16 lAh[4096], lAl[4096], lBh[4096], lBl[4096];
  const int tid = threadIdx.x;
  const int wid = tid >> 6, lane = tid & 63;
  const int wm = wid >> 1, wn = wid & 1;
  const int lg = lane >> 4, lm = lane & 15;
  const int mbase = blockIdx.y * 128, nbase = blockIdx.x * 128;

  f32x4 acc[4][4];
  const f32x4 zero = {0.f, 0.f, 0.f, 0.f};
#pragma unroll
  for (int a = 0; a < 4; ++a)
#pragma unroll
    for (int b = 0; b < 4; ++b) acc[a][b] = zero;

  for (int k0 = 0; k0 < K; k0 += 32) {
    stage_tile(Ah, lAh, mbase, M - 1, K, k0, tid);
    stage_tile(Al, lAl, mbase, M - 1, K, k0, tid);
    stage_tile(Bh, lBh, nbase, Nn - 1, K, k0, tid);
    stage_tile(Bl, lBl, nbase, Nn - 1, K, k0, tid);
    __syncthreads();
    bf16x8 afh[4], afl[4], bfh[4], bfl[4];
#pragma unroll
    for (int f = 0; f < 4; ++f) {
      int ra = wm * 64 + f * 16 + lm, rb = wn * 64 + f * 16 + lm;
      afh[f] = *(const bf16x8*)&lAh[swz_off(ra, lg)];
      afl[f] = *(const bf16x8*)&lAl[swz_off(ra, lg)];
      bfh[f] = *(const bf16x8*)&lBh[swz_off(rb, lg)];
      bfl[f] = *(const bf16x8*)&lBl[swz_off(rb, lg)];
    }
#pragma unroll
    for (int fm = 0; fm < 4; ++fm)
#pragma unroll
      for (int fn = 0; fn < 4; ++fn) {
        acc[fm][fn] = MFMA16(afh[fm], bfh[fn], acc[fm][fn]);
        acc[fm][fn] = MFMA16(afh[fm], bfl[fn], acc[fm][fn]);
        acc[fm][fn] = MFMA16(afl[fm], bfh[fn], acc[fm][fn]);
      }
    __syncthreads();
  }

  const int which = (EPI == 0) ? (nbase >> 10) : 1;
  const bool odd = (lm & 1);

#pragma unroll
  for (int fm = 0; fm < 4; ++fm)
#pragma unroll
    for (int fn = 0; fn < 4; ++fn) {
      int col = nbase + wn * 64 + fn * 16 + lm;
      float bv = bias[col];
      int h2 = (col >> 6) & 15, d2 = col & 63;
#pragma unroll
      for (int i = 0; i < 4; ++i) {
        int row = mbase + wm * 64 + fm * 16 + lg * 4 + i;
        float v = acc[fm][fn][i] + bv;
        float partner = __shfl_xor(v, 1);  // neighbor column (re<->im), uniform exec
        if (row < M) {
          if (EPI == 1) {
            outf[(size_t)row * Nn + col] = v;
          } else {
            int b2 = row / Ntok, t2 = row - b2 * Ntok;
            int bh2 = b2 * 16 + h2;
            if (which == 2) {  // v: f16 single, row-major
              ov[((size_t)bh2 * Ntok + t2) * 64 + d2] = f2h(v);
            } else {
              // rope: even lane = re, odd lane = im
              float out = v;
              if (t2 > 0) {
                float2 cs = cst[((size_t)(b2 << 11) + (t2 - 1)) * 32 + (d2 >> 1)];
                out = v * cs.x + (odd ? partner * cs.y : -partner * cs.y);
              }
              if (which == 0) {  // q: fold softmax scale & exp2 conversion, f16 single
                out *= 0.18033688011112042f;  // 0.125 * log2(e)
                oq[((size_t)bh2 * Ntok + t2) * 64 + d2] = f2h(out);
              } else {  // k: f16 single, padded row allocation [bh][NP][64]
                ok[((size_t)bh2 * NP + t2) * 64 + d2] = f2h(out);
              }
            }
          }
        }
      }
    }
}

// ---------------- flash attention v5: 8-wave blocks, 256 q-rows, KVBLK=64, 2-phase ----------------
// K tile LDS (8KB): chunk rK*64+key -> K[key][rK*8..+8]  (rK = d-octet 0..7)
// V tile LDS (8KB): chunk kr*64+d   -> V^T[d][kv+kr*8..+8] (kr = key-octet 0..7)
// (bank map already 2-way-clean: bank = lm*4 + 16B within; lm and lm+8 share = free)
template <bool DO_STAGE, bool TAIL>
__device__ __forceinline__ void attn_tile(
    int kv0, int kvn,
    const u16* Kc, const u16* Vc, u16* Kn, u16* Vn,
    const u16* kgb, const u16* vgb,
    int tid, int lg, int lm, int kvbase,
    const f16x8 (&qf16)[2][2],
    float (&m_)[2], float (&l_)[2], f32x4 (&oacc)[2][4],
    unsigned (*pexw)[4], int N) {
  if (DO_STAGE) {  // stage NEXT tile (other buffer); latency hides under this tile's compute
    __builtin_amdgcn_global_load_lds(
        (const __attribute__((address_space(1))) void*)(kgb + (size_t)kvn * 64),
        (__attribute__((address_space(3))) void*)(Kn + tid * 8), 16, 0, 0);
    __builtin_amdgcn_global_load_lds(
        (const __attribute__((address_space(1))) void*)(vgb + kvn),
        (__attribute__((address_space(3))) void*)(Vn + tid * 8), 16, 0, 0);
  }

  const f32x4 zero = {0.f, 0.f, 0.f, 0.f};
  f32x4 s[2][4];
#pragma unroll
  for (int qf = 0; qf < 2; ++qf)
#pragma unroll
    for (int cf = 0; cf < 4; ++cf) s[qf][cf] = zero;
#pragma unroll
  for (int cf = 0; cf < 4; ++cf)
#pragma unroll
    for (int dk = 0; dk < 2; ++dk) {
      f16x8 kf = *(const f16x8*)&Kc[kvbase + dk * 2048 + cf * 128];
      s[0][cf] = MFMAH(kf, qf16[0][dk], s[0][cf]);
      s[1][cf] = MFMAH(kf, qf16[1][dk], s[1][cf]);
    }
  if (TAIL) {
#pragma unroll
    for (int qf = 0; qf < 2; ++qf)
#pragma unroll
      for (int cf = 0; cf < 4; ++cf)
#pragma unroll
        for (int i = 0; i < 4; ++i)
          if (kv0 + cf * 16 + lg * 4 + i >= N) s[qf][cf][i] = -1e30f;
  }

  f16x8 pb[2][2];  // [qf][ks]
  const int ga = (lg & 1) * 2, gb = ga + 1;
  const int cfs2 = (lg >> 1) * 2;
#pragma unroll
  for (int qf = 0; qf < 2; ++qf) {
    float mx = s[qf][0][0];
#pragma unroll
    for (int cf = 0; cf < 4; ++cf)
#pragma unroll
      for (int i = 0; i < 4; ++i) mx = fmaxf(mx, s[qf][cf][i]);
    mx = fmaxf(mx, __shfl_xor(mx, 16));
    mx = fmaxf(mx, __shfl_xor(mx, 32));
    float mr = m_[qf];
    bool nore = __all(mx - mr <= 8.f) != 0;  // defer-max, THR=8 in log2 domain
    float mnew = nore ? mr : fmaxf(mr, mx);
    float p[16];
#pragma unroll
    for (int cf = 0; cf < 4; ++cf)
#pragma unroll
      for (int i = 0; i < 4; ++i)
        p[cf * 4 + i] = __builtin_amdgcn_exp2f(s[qf][cf][i] - mnew);
    float ps = 0.f;
#pragma unroll
    for (int j = 0; j < 16; ++j) ps += p[j];
    ps += __shfl_xor(ps, 16);
    ps += __shfl_xor(ps, 32);
    if (nore) {
      l_[qf] += ps;
    } else {
      float sc = __builtin_amdgcn_exp2f(mr - mnew);
      l_[qf] = l_[qf] * sc + ps;
      m_[qf] = mnew;
#pragma unroll
      for (int c = 0; c < 4; ++c)
#pragma unroll
        for (int i = 0; i < 4; ++i) oacc[qf][c][i] *= sc;
    }
    // pack P -> f16, redistribute to B-frag via wave-private LDS (DS in-order per wave)
#pragma unroll
    for (int ks = 0; ks < 2; ++ks) {
      uint4 uw;
      uw.x = pk_h(p[ks * 8 + 0], p[ks * 8 + 1]);
      uw.y = pk_h(p[ks * 8 + 2], p[ks * 8 + 3]);
      uw.z = pk_h(p[ks * 8 + 4], p[ks * 8 + 5]);
      uw.w = pk_h(p[ks * 8 + 6], p[ks * 8 + 7]);
      *(uint4*)&pexw[lg * 16 + lm][0] = uw;
      uint2 r0 = *(const uint2*)&pexw[ga * 16 + lm][cfs2];
      uint2 r1 = *(const uint2*)&pexw[gb * 16 + lm][cfs2];
      uint4 pu = make_uint4(r0.x, r0.y, r1.x, r1.y);
      pb[qf][ks] = __builtin_bit_cast(f16x8, pu);
    }
  }

#pragma unroll
  for (int c = 0; c < 4; ++c)
#pragma unroll
    for (int ks = 0; ks < 2; ++ks) {
      f16x8 vh = *(const f16x8*)&Vc[kvbase + ks * 2048 + c * 128];
      oacc[0][c] = MFMAH(vh, pb[0][ks], oacc[0][c]);
      oacc[1][c] = MFMAH(vh, pb[1][ks], oacc[1][c]);
    }
}

__global__ __launch_bounds__(512, 4) void attn_kernel(
    const u16* __restrict__ qh, const u16* __restrict__ kh, const u16* __restrict__ vth,
    u16* __restrict__ outh, u16* __restrict__ outl, int N, int NP) {
  __shared__ u16 K0[4096], V0[4096], K1[4096], V1[4096];
  __shared__ unsigned pexm[8][64][4];

  const int id = blockIdx.x;
  const int swz = (id & 7) * 72 + (id >> 3);  // XCD-bijective (576 = 8*72)
  const int qblk = swz % 9;
  const int bh = swz / 9;
  const int b = bh >> 4, h = bh & 15;
  const int tid = threadIdx.x;
  const int wid = tid >> 6, lane = tid & 63;
  const int lg = lane >> 4, lm = lane & 15;
  const int qbase = qblk * 256 + wid * 32;
  const size_t qoff = (size_t)bh * N * 64;
  const size_t koff = (size_t)bh * NP * 64;
  const size_t voff = (size_t)bh * 64 * NP;

  // staging sources: K thread t -> row (t&63), d-octet (t>>6); V thread t -> d (t&63), key-octet (t>>6)
  const int jK = tid & 63, rK = tid >> 6;
  const u16* kgb = kh + koff + (size_t)jK * 64 + rK * 8;
  const u16* vgb = vth + voff + (size_t)jK * NP + rK * 8;
  const int kvbase = lg * 512 + lm * 8;  // + dk|ks*2048 + cf|c*128

  f16x8 qf16[2][2];
#pragma unroll
  for (int qf = 0; qf < 2; ++qf) {
    int qr = qbase + qf * 16 + lm;
    if (qr > N - 1) qr = N - 1;
    const u16* qp = qh + qoff + (size_t)qr * 64 + lg * 8;
    qf16[qf][0] = *(const f16x8*)(qp);
    qf16[qf][1] = *(const f16x8*)(qp + 32);
  }

  const f32x4 zero = {0.f, 0.f, 0.f, 0.f};
  f32x4 oacc[2][4];
#pragma unroll
  for (int qf = 0; qf < 2; ++qf)
#pragma unroll
    for (int c = 0; c < 4; ++c) oacc[qf][c] = zero;
  float m_[2] = {-1e30f, -1e30f}, l_[2] = {0.f, 0.f};
  unsigned(*pexw)[4] = &pexm[wid][0];

  // prologue: stage tile 0 into buffer 0
  __builtin_amdgcn_global_load_lds(
      (const __attribute__((address_space(1))) void*)kgb,
      (__attribute__((address_space(3))) void*)(K0 + tid * 8), 16, 0, 0);
  __builtin_amdgcn_global_load_lds(
      (const __attribute__((address_space(1))) void*)vgb,
      (__attribute__((address_space(3))) void*)(V0 + tid * 8), 16, 0, 0);
  asm volatile("s_waitcnt vmcnt(0)" ::: "memory");
  __builtin_amdgcn_s_barrier();

  // tiles 0..31 in pairs (stage t+1 during t), tile 32 = tail (keys 2048..2111, padded)
  for (int t = 0; t < 32; t += 2) {
    attn_tile<true, false>(t * 64, (t + 1) * 64, K0, V0, K1, V1, kgb, vgb,
                           tid, lg, lm, kvbase, qf16, m_, l_, oacc, pexw, N);
    asm volatile("s_waitcnt vmcnt(0)" ::: "memory");
    __builtin_amdgcn_s_barrier();
    attn_tile<true, false>((t + 1) * 64, (t + 2) * 64, K1, V1, K0, V0, kgb, vgb,
                           tid, lg, lm, kvbase, qf16, m_, l_, oacc, pexw, N);
    asm volatile("s_waitcnt vmcnt(0)" ::: "memory");
    __builtin_amdgcn_s_barrier();
  }
  attn_tile<false, true>(32 * 64, 0, K0, V0, K1, V1, kgb, vgb,
                         tid, lg, lm, kvbase, qf16, m_, l_, oacc, pexw, N);

  // epilogue: O/l -> bf16 hi/lo (feeds final bf16x3 GEMM)
#pragma unroll
  for (int qf = 0; qf < 2; ++qf) {
    int t = qbase + qf * 16 + lm;
    if (t < N) {
      float rl = 1.f / l_[qf];
      size_t rowoff = ((size_t)(b * N + t)) * 1024 + h * 64 + lg * 4;
#pragma unroll
      for (int c = 0; c < 4; ++c) {
        float v0 = oacc[qf][c][0] * rl, v1 = oacc[qf][c][1] * rl;
        float v2 = oacc[qf][c][2] * rl, v3 = oacc[qf][c][3] * rl;
        unsigned h01 = cvt_pk(v0, v1), h23 = cvt_pk(v2, v3);
        unsigned l01 = cvt_pk(v0 - __uint_as_float(h01 << 16),
                              v1 - __uint_as_float(h01 & 0xffff0000u));
        unsigned l23 = cvt_pk(v2 - __uint_as_float(h23 << 16),
                              v3 - __uint_as_float(h23 & 0xffff0000u));
        *(uint2*)(outh + rowoff + c * 16) = make_uint2(h01, h23);
        *(uint2*)(outl + rowoff + c * 16) = make_uint2(l01, l23);
      }
    }
  }
}

// ---------------- orchestration ----------------
extern "C" void kernel_launch(void* const* d_in, const int* in_sizes, int n_in,
                              void* d_out, int out_size, void* d_ws, size_t ws_size,
                              hipStream_t stream) {
  const float* x     = (const float*)d_in[0];
  const int*   pos   = (const int*)  d_in[1];
  const float* w_qkv = (const float*)d_in[2];
  const float* b_qkv = (const float*)d_in[3];
  const float* w_fc  = (const float*)d_in[4];
  const float* b_fc  = (const float*)d_in[5];
  (void)in_sizes; (void)n_in; (void)out_size; (void)ws_size;

  const int B = 4, N = 2049, NP = 2112;  // NP = 33*64 (KVBLK=64 tiles)
  const long EL = (long)B * N * 1024;       // 8,392,704
  const long ELP = (long)B * 16 * NP * 64;  // padded K elems

  char* base = (char*)d_ws;
  size_t off = 0;
  auto alloc = [&](size_t bytes) -> void* {
    void* p = base + off;
    off += (bytes + 255) & ~(size_t)255;
    return p;
  };
  u16* qhh = (u16*)alloc(EL * 2);                      // q f16 (scaled)
  u16* khh = (u16*)alloc(ELP * 2);                     // k f16 (padded rows)
  u16* vbh = (u16*)alloc(EL * 2);                      // v f16 row-major
  u16* vth = (u16*)alloc((size_t)64 * 64 * NP * 2);    // v^T f16 padded cols
  u16* xh  = (u16*)alloc(EL * 2);                      // x / attn-out bf16 hi
  u16* xl  = (u16*)alloc(EL * 2);                      // x / attn-out bf16 lo
  u16* wqh = (u16*)alloc((size_t)3072 * 1024 * 2);
  u16* wql = (u16*)alloc((size_t)3072 * 1024 * 2);
  u16* wfh = (u16*)alloc((size_t)1024 * 1024 * 2);
  u16* wfl = (u16*)alloc((size_t)1024 * 1024 * 2);
  float2* cst = (float2*)alloc((size_t)B * 2048 * 32 * 8);

  // 1. split inputs; build cos/sin table (one fp64 sincos per (b,t,i), shared by 16 heads)
  split_kernel<<<2048, 256, 0, stream>>>(x, xh, xl, EL / 4);
  split_kernel<<<1024, 256, 0, stream>>>(w_qkv, wqh, wql, (long)3072 * 1024 / 4);
  split_kernel<<<512, 256, 0, stream>>>(w_fc, wfh, wfl, (long)1024 * 1024 / 4);
  cs_table_kernel<<<(B * 2048 * 32) / 256, 256, 0, stream>>>(pos, cst);
  // 2. fused QKV projection with fused RoPE + f16 q/k/v epilogue
  gemm_bf16x3<0><<<dim3(24, 65), 256, 0, stream>>>(xh, xl, wqh, wql, b_qkv, cst, nullptr,
                                                   qhh, khh, vbh, 8196, 3072, 1024, N, NP);
  // 3. pad K rows [N,NP); transpose+pad V (f16 -> [bh][64][NP])
  kpad_kernel<<<(64 * (NP - N) * 32 + 255) / 256, 256, 0, stream>>>(khh, N, NP);
  vtransT_kernel<<<dim3(NP / 64, 64), 256, 0, stream>>>(vbh, vth, N, NP);
  // 4. flash attention (f16 core, 8-wave/256-row blocks) -> bf16 hi/lo, reusing xh/xl
  attn_kernel<<<dim3(576), 512, 0, stream>>>(qhh, khh, vth, xh, xl, N, NP);
  // 5. output projection -> d_out
  gemm_bf16x3<1><<<dim3(8, 65), 256, 0, stream>>>(xh, xl, wfh, wfl, b_fc, nullptr,
                                                  (float*)d_out, nullptr, nullptr, nullptr,
                                                  8196, 1024, 1024, N, NP);
}

// Round 8
// 404.811 us; speedup vs baseline: 3.2924x; 1.2110x over previous
//
#include <hip/hip_runtime.h>

typedef unsigned short u16;
typedef __attribute__((ext_vector_type(8))) _Float16 f16x8;
typedef __attribute__((ext_vector_type(4))) float f32x4;

#define MFMAH(a, b, c) __builtin_amdgcn_mfma_f32_16x16x32_f16((a), (b), (c), 0, 0, 0)

__device__ __forceinline__ u16 f2h(float f) {
  _Float16 h = (_Float16)f;  // v_cvt_f16_f32, RNE
  return __builtin_bit_cast(u16, h);
}
__device__ __forceinline__ float h2f(u16 h) {
  return (float)__builtin_bit_cast(_Float16, h);
}
__device__ __forceinline__ unsigned pk_h(float a, float b) {
  return (unsigned)f2h(a) | ((unsigned)f2h(b) << 16);
}

// ---------------- x: fp32 -> f16 hi + f16 lo (x = hi + lo exact to ~2^-23) ----------------
__global__ void splitf16_kernel(const float* __restrict__ in, u16* __restrict__ hi,
                                u16* __restrict__ lo, long n4) {
  long stride = (long)gridDim.x * blockDim.x;
  for (long i = (long)blockIdx.x * blockDim.x + threadIdx.x; i < n4; i += stride) {
    float4 v = ((const float4*)in)[i];
    ushort4 h, l;
    h.x = f2h(v.x); l.x = f2h(v.x - h2f(h.x));
    h.y = f2h(v.y); l.y = f2h(v.y - h2f(h.y));
    h.z = f2h(v.z); l.z = f2h(v.z - h2f(h.z));
    h.w = f2h(v.w); l.w = f2h(v.w - h2f(h.w));
    ((ushort4*)hi)[i] = h;
    ((ushort4*)lo)[i] = l;
  }
}

// ---------------- weights: fp32 -> f16 single ----------------
__global__ void castf16_kernel(const float* __restrict__ in, u16* __restrict__ out, long n4) {
  long stride = (long)gridDim.x * blockDim.x;
  for (long i = (long)blockIdx.x * blockDim.x + threadIdx.x; i < n4; i += stride) {
    float4 v = ((const float4*)in)[i];
    ushort4 h;
    h.x = f2h(v.x); h.y = f2h(v.y); h.z = f2h(v.z); h.w = f2h(v.w);
    ((ushort4*)out)[i] = h;
  }
}

// ---------------- cos/sin table: (b, t-1, i) -> float2(c,s); 16 heads share positions ----------------
__global__ void cs_table_kernel(const int* __restrict__ pos, float2* __restrict__ cst) {
  int idx = blockIdx.x * 256 + threadIdx.x;  // exactly B*2048*32 threads
  int i = idx & 31;
  int r = idx >> 5;
  int ti = r & 2047;
  int b = r >> 11;
  int p = pos[b * 2048 + ti];
  // replicate reference fp32 rounding of freq and angle, then exact trig
  float fr = (float)pow(10000.0, -(double)i / 32.0);
  float angf = (float)p * fr;
  double sd, cd;
  sincos((double)angf, &sd, &cd);
  cst[idx] = make_float2((float)cd, (float)sd);
}

// ---------------- K pad rows [N, NP): zero (f16 single) ----------------
__global__ void kpad_kernel(u16* __restrict__ kh, int N, int NP) {
  const int per_bh = (NP - N) * 32;  // u32 words per bh
  int idx = blockIdx.x * 256 + threadIdx.x;
  if (idx >= 64 * per_bh) return;
  int bh = idx / per_bh, r = idx - bh * per_bh;
  size_t u = (((size_t)bh * NP + N) * 64 >> 1) + r;
  ((unsigned*)kh)[u] = 0;
}

// ---------------- V transpose: f16 [bh][N][64] -> [bh][64][NP], zero-padded ----------------
__global__ __launch_bounds__(256) void vtransT_kernel(const u16* __restrict__ vb_,
                                                      u16* __restrict__ ot, int N, int NP) {
  __shared__ u16 tile[64][72];
  const int bh = blockIdx.y;
  const int t0 = blockIdx.x * 64;
  const u16* ih = vb_ + (size_t)bh * N * 64;
#pragma unroll
  for (int p = 0; p < 4; ++p) {
    int idx = p * 256 + threadIdx.x;  // 1024 chunks of 4 u16
    int tloc = idx >> 4, c = (idx & 15) * 4;
    int t = t0 + tloc;
    ushort4 a = make_ushort4(0, 0, 0, 0);
    if (t < N) a = *(const ushort4*)(ih + (size_t)t * 64 + c);
    *(ushort4*)&tile[tloc][c] = a;
  }
  __syncthreads();
  u16* oh = ot + (size_t)bh * 64 * NP;
#pragma unroll
  for (int p = 0; p < 4; ++p) {
    int idx = p * 256 + threadIdx.x;  // d (64) x tquad (16)
    int d = idx >> 4, tq = (idx & 15) * 4;
    int t = t0 + tq;
    if (t < NP) {
      ushort4 a;
      a.x = tile[tq + 0][d]; a.y = tile[tq + 1][d];
      a.z = tile[tq + 2][d]; a.w = tile[tq + 3][d];
      *(ushort4*)(oh + (size_t)d * NP + t) = a;
    }
  }
}

// ---------------- f16x2 emulated-fp32 GEMM: C = (Ah+Al)(MxK) * W(NxK)^T + bias ----------------
// A = f16 hi/lo pair (exact to ~2^-23); W = single f16 (err ~2^-12 rel, dominates; within budget).
// 2 MFMAs per fragment pair. Stage-early double-buffered LDS (T3-lite): next tile's
// global_load_lds issued before current tile's compute; one syncthreads per phase drains it
// AFTER ~700cy of compute -> L2 latency hidden (R7 lesson: conflict fix was null, drain was the wall).
// T2 source-side swizzle kept (conflicts = 0).
__device__ __forceinline__ void stage_tile(const u16* __restrict__ g, u16* l,
                                           int row0, int rmax, int K, int k0, int tid) {
#pragma unroll
  for (int t = 0; t < 2; ++t) {
    int c = t * 256 + tid;
    int row = c >> 2;
    int kc = (((c & 3) ^ ((c >> 3) & 3)) << 3);  // pre-swizzled source granule
    int gr = row0 + row;
    if (gr > rmax) gr = rmax;
    const u16* gp = g + (size_t)gr * K + (k0 + kc);
    __builtin_amdgcn_global_load_lds((const __attribute__((address_space(1))) void*)gp,
                                     (__attribute__((address_space(3))) void*)(l + c * 8),
                                     16, 0, 0);
  }
}
// swizzled fragment offset (u16 units): row R (stride 32 u16), granule lg
__device__ __forceinline__ int swz_off(int R, int lg) {
  return R * 32 + ((lg ^ ((R >> 1) & 3)) << 3);
}

__device__ __forceinline__ void stage3(const u16* Ah, const u16* Al, const u16* Bw,
                                       u16* lAh, u16* lAl, u16* lBw,
                                       int mbase, int nbase, int M, int Nn, int K, int k0,
                                       int tid) {
  stage_tile(Ah, lAh, mbase, M - 1, K, k0, tid);
  stage_tile(Al, lAl, mbase, M - 1, K, k0, tid);
  stage_tile(Bw, lBw, nbase, Nn - 1, K, k0, tid);
}

__device__ __forceinline__ void gemm_compute(const u16* lAh, const u16* lAl, const u16* lBw,
                                             int wm, int wn, int lm, int lg,
                                             f32x4 (&acc)[4][4]) {
  f16x8 afh[4], afl[4], bw[4];
#pragma unroll
  for (int f = 0; f < 4; ++f) {
    int ra = wm * 64 + f * 16 + lm, rb = wn * 64 + f * 16 + lm;
    afh[f] = *(const f16x8*)&lAh[swz_off(ra, lg)];
    afl[f] = *(const f16x8*)&lAl[swz_off(ra, lg)];
    bw[f] = *(const f16x8*)&lBw[swz_off(rb, lg)];
  }
#pragma unroll
  for (int fm = 0; fm < 4; ++fm)
#pragma unroll
    for (int fn = 0; fn < 4; ++fn) {
      acc[fm][fn] = MFMAH(afh[fm], bw[fn], acc[fm][fn]);
      acc[fm][fn] = MFMAH(afl[fm], bw[fn], acc[fm][fn]);
    }
}

template <int EPI>
__global__ __launch_bounds__(256) void gemm_f16x2(
    const u16* __restrict__ Ah, const u16* __restrict__ Al, const u16* __restrict__ Bw,
    const float* __restrict__ bias, const float2* __restrict__ cst,
    float* __restrict__ outf,
    u16* __restrict__ oq, u16* __restrict__ ok, u16* __restrict__ ov,
    int M, int Nn, int K, int Ntok, int NP) {
  __shared__ u16 A0h[4096], A0l[4096], B0w[4096];
  __shared__ u16 A1h[4096], A1l[4096], B1w[4096];
  const int tid = threadIdx.x;
  const int wid = tid >> 6, lane = tid & 63;
  const int wm = wid >> 1, wn = wid & 1;
  const int lg = lane >> 4, lm = lane & 15;
  // XCD-bijective 1D swizzle (grid % 8 == 0): consecutive swz on one XCD share A panels
  const int id = blockIdx.x;
  const int chunk = gridDim.x >> 3, nx = Nn >> 7;
  const int swz = (id & 7) * chunk + (id >> 3);
  const int mbase = (swz / nx) * 128, nbase = (swz % nx) * 128;

  f32x4 acc[4][4];
  const f32x4 zero = {0.f, 0.f, 0.f, 0.f};
#pragma unroll
  for (int a = 0; a < 4; ++a)
#pragma unroll
    for (int b = 0; b < 4; ++b) acc[a][b] = zero;

  // prologue: stage k=0 into buffer 0
  stage3(Ah, Al, Bw, A0h, A0l, B0w, mbase, nbase, M, Nn, K, 0, tid);
  __syncthreads();

  for (int k0 = 0; k0 < K; k0 += 64) {
    // phase A: stage k0+32 -> buf1, compute buf0 (k0)
    if (k0 + 32 < K)
      stage3(Ah, Al, Bw, A1h, A1l, B1w, mbase, nbase, M, Nn, K, k0 + 32, tid);
    gemm_compute(A0h, A0l, B0w, wm, wn, lm, lg, acc);
    __syncthreads();
    // phase B: stage k0+64 -> buf0, compute buf1 (k0+32)
    if (k0 + 64 < K)
      stage3(Ah, Al, Bw, A0h, A0l, B0w, mbase, nbase, M, Nn, K, k0 + 64, tid);
    gemm_compute(A1h, A1l, B1w, wm, wn, lm, lg, acc);
    __syncthreads();
  }

  const int which = (EPI == 0) ? (nbase >> 10) : 1;
  const bool odd = (lm & 1);

#pragma unroll
  for (int fm = 0; fm < 4; ++fm)
#pragma unroll
    for (int fn = 0; fn < 4; ++fn) {
      int col = nbase + wn * 64 + fn * 16 + lm;
      float bv = bias[col];
      int h2 = (col >> 6) & 15, d2 = col & 63;
#pragma unroll
      for (int i = 0; i < 4; ++i) {
        int row = mbase + wm * 64 + fm * 16 + lg * 4 + i;
        float v = acc[fm][fn][i] + bv;
        float partner = __shfl_xor(v, 1);  // neighbor column (re<->im), uniform exec
        if (row < M) {
          if (EPI == 1) {
            outf[(size_t)row * Nn + col] = v;
          } else {
            int b2 = row / Ntok, t2 = row - b2 * Ntok;
            int bh2 = b2 * 16 + h2;
            if (which == 2) {  // v: f16 single, row-major
              ov[((size_t)bh2 * Ntok + t2) * 64 + d2] = f2h(v);
            } else {
              // rope: even lane = re, odd lane = im
              float out = v;
              if (t2 > 0) {
                float2 cs = cst[((size_t)(b2 << 11) + (t2 - 1)) * 32 + (d2 >> 1)];
                out = v * cs.x + (odd ? partner * cs.y : -partner * cs.y);
              }
              if (which == 0) {  // q: fold softmax scale & exp2 conversion, f16 single
                out *= 0.18033688011112042f;  // 0.125 * log2(e)
                oq[((size_t)bh2 * Ntok + t2) * 64 + d2] = f2h(out);
              } else {  // k: f16 single, padded row allocation [bh][NP][64]
                ok[((size_t)bh2 * NP + t2) * 64 + d2] = f2h(out);
              }
            }
          }
        }
      }
    }
}

// ---------------- flash attention v5: 8-wave blocks, 256 q-rows, KVBLK=64, 2-phase ----------------
// K tile LDS (8KB): chunk rK*64+key -> K[key][rK*8..+8]  (rK = d-octet 0..7)
// V tile LDS (8KB): chunk kr*64+d   -> V^T[d][kv+kr*8..+8] (kr = key-octet 0..7)
template <bool DO_STAGE, bool TAIL>
__device__ __forceinline__ void attn_tile(
    int kv0, int kvn,
    const u16* Kc, const u16* Vc, u16* Kn, u16* Vn,
    const u16* kgb, const u16* vgb,
    int tid, int lg, int lm, int kvbase,
    const f16x8 (&qf16)[2][2],
    float (&m_)[2], float (&l_)[2], f32x4 (&oacc)[2][4],
    unsigned (*pexw)[4], int N) {
  if (DO_STAGE) {  // stage NEXT tile (other buffer); latency hides under this tile's compute
    __builtin_amdgcn_global_load_lds(
        (const __attribute__((address_space(1))) void*)(kgb + (size_t)kvn * 64),
        (__attribute__((address_space(3))) void*)(Kn + tid * 8), 16, 0, 0);
    __builtin_amdgcn_global_load_lds(
        (const __attribute__((address_space(1))) void*)(vgb + kvn),
        (__attribute__((address_space(3))) void*)(Vn + tid * 8), 16, 0, 0);
  }

  const f32x4 zero = {0.f, 0.f, 0.f, 0.f};
  f32x4 s[2][4];
#pragma unroll
  for (int qf = 0; qf < 2; ++qf)
#pragma unroll
    for (int cf = 0; cf < 4; ++cf) s[qf][cf] = zero;
#pragma unroll
  for (int cf = 0; cf < 4; ++cf)
#pragma unroll
    for (int dk = 0; dk < 2; ++dk) {
      f16x8 kf = *(const f16x8*)&Kc[kvbase + dk * 2048 + cf * 128];
      s[0][cf] = MFMAH(kf, qf16[0][dk], s[0][cf]);
      s[1][cf] = MFMAH(kf, qf16[1][dk], s[1][cf]);
    }
  if (TAIL) {
#pragma unroll
    for (int qf = 0; qf < 2; ++qf)
#pragma unroll
      for (int cf = 0; cf < 4; ++cf)
#pragma unroll
        for (int i = 0; i < 4; ++i)
          if (kv0 + cf * 16 + lg * 4 + i >= N) s[qf][cf][i] = -1e30f;
  }

  f16x8 pb[2][2];  // [qf][ks]
  const int ga = (lg & 1) * 2, gb = ga + 1;
  const int cfs2 = (lg >> 1) * 2;
#pragma unroll
  for (int qf = 0; qf < 2; ++qf) {
    float mx = s[qf][0][0];
#pragma unroll
    for (int cf = 0; cf < 4; ++cf)
#pragma unroll
      for (int i = 0; i < 4; ++i) mx = fmaxf(mx, s[qf][cf][i]);
    mx = fmaxf(mx, __shfl_xor(mx, 16));
    mx = fmaxf(mx, __shfl_xor(mx, 32));
    float mr = m_[qf];
    bool nore = __all(mx - mr <= 8.f) != 0;  // defer-max, THR=8 in log2 domain
    float mnew = nore ? mr : fmaxf(mr, mx);
    float p[16];
#pragma unroll
    for (int cf = 0; cf < 4; ++cf)
#pragma unroll
      for (int i = 0; i < 4; ++i)
        p[cf * 4 + i] = __builtin_amdgcn_exp2f(s[qf][cf][i] - mnew);
    float ps = 0.f;
#pragma unroll
    for (int j = 0; j < 16; ++j) ps += p[j];
    ps += __shfl_xor(ps, 16);
    ps += __shfl_xor(ps, 32);
    if (nore) {
      l_[qf] += ps;
    } else {
      float sc = __builtin_amdgcn_exp2f(mr - mnew);
      l_[qf] = l_[qf] * sc + ps;
      m_[qf] = mnew;
#pragma unroll
      for (int c = 0; c < 4; ++c)
#pragma unroll
        for (int i = 0; i < 4; ++i) oacc[qf][c][i] *= sc;
    }
    // pack P -> f16, redistribute to B-frag via wave-private LDS (DS in-order per wave)
#pragma unroll
    for (int ks = 0; ks < 2; ++ks) {
      uint4 uw;
      uw.x = pk_h(p[ks * 8 + 0], p[ks * 8 + 1]);
      uw.y = pk_h(p[ks * 8 + 2], p[ks * 8 + 3]);
      uw.z = pk_h(p[ks * 8 + 4], p[ks * 8 + 5]);
      uw.w = pk_h(p[ks * 8 + 6], p[ks * 8 + 7]);
      *(uint4*)&pexw[lg * 16 + lm][0] = uw;
      uint2 r0 = *(const uint2*)&pexw[ga * 16 + lm][cfs2];
      uint2 r1 = *(const uint2*)&pexw[gb * 16 + lm][cfs2];
      uint4 pu = make_uint4(r0.x, r0.y, r1.x, r1.y);
      pb[qf][ks] = __builtin_bit_cast(f16x8, pu);
    }
  }

#pragma unroll
  for (int c = 0; c < 4; ++c)
#pragma unroll
    for (int ks = 0; ks < 2; ++ks) {
      f16x8 vh = *(const f16x8*)&Vc[kvbase + ks * 2048 + c * 128];
      oacc[0][c] = MFMAH(vh, pb[0][ks], oacc[0][c]);
      oacc[1][c] = MFMAH(vh, pb[1][ks], oacc[1][c]);
    }
}

__global__ __launch_bounds__(512, 4) void attn_kernel(
    const u16* __restrict__ qh, const u16* __restrict__ kh, const u16* __restrict__ vth,
    u16* __restrict__ outh, u16* __restrict__ outl, int N, int NP) {
  __shared__ u16 K0[4096], V0[4096], K1[4096], V1[4096];
  __shared__ unsigned pexm[8][64][4];

  const int id = blockIdx.x;
  const int swz = (id & 7) * 72 + (id >> 3);  // XCD-bijective (576 = 8*72)
  const int qblk = swz % 9;
  const int bh = swz / 9;
  const int b = bh >> 4, h = bh & 15;
  const int tid = threadIdx.x;
  const int wid = tid >> 6, lane = tid & 63;
  const int lg = lane >> 4, lm = lane & 15;
  const int qbase = qblk * 256 + wid * 32;
  const size_t qoff = (size_t)bh * N * 64;
  const size_t koff = (size_t)bh * NP * 64;
  const size_t voff = (size_t)bh * 64 * NP;

  // staging sources: K thread t -> row (t&63), d-octet (t>>6); V thread t -> d (t&63), key-octet (t>>6)
  const int jK = tid & 63, rK = tid >> 6;
  const u16* kgb = kh + koff + (size_t)jK * 64 + rK * 8;
  const u16* vgb = vth + voff + (size_t)jK * NP + rK * 8;
  const int kvbase = lg * 512 + lm * 8;  // + dk|ks*2048 + cf|c*128

  f16x8 qf16[2][2];
#pragma unroll
  for (int qf = 0; qf < 2; ++qf) {
    int qr = qbase + qf * 16 + lm;
    if (qr > N - 1) qr = N - 1;
    const u16* qp = qh + qoff + (size_t)qr * 64 + lg * 8;
    qf16[qf][0] = *(const f16x8*)(qp);
    qf16[qf][1] = *(const f16x8*)(qp + 32);
  }

  const f32x4 zero = {0.f, 0.f, 0.f, 0.f};
  f32x4 oacc[2][4];
#pragma unroll
  for (int qf = 0; qf < 2; ++qf)
#pragma unroll
    for (int c = 0; c < 4; ++c) oacc[qf][c] = zero;
  float m_[2] = {-1e30f, -1e30f}, l_[2] = {0.f, 0.f};
  unsigned(*pexw)[4] = &pexm[wid][0];

  // prologue: stage tile 0 into buffer 0
  __builtin_amdgcn_global_load_lds(
      (const __attribute__((address_space(1))) void*)kgb,
      (__attribute__((address_space(3))) void*)(K0 + tid * 8), 16, 0, 0);
  __builtin_amdgcn_global_load_lds(
      (const __attribute__((address_space(1))) void*)vgb,
      (__attribute__((address_space(3))) void*)(V0 + tid * 8), 16, 0, 0);
  asm volatile("s_waitcnt vmcnt(0)" ::: "memory");
  __builtin_amdgcn_s_barrier();

  // tiles 0..31 in pairs (stage t+1 during t), tile 32 = tail (keys 2048..2111, padded)
  for (int t = 0; t < 32; t += 2) {
    attn_tile<true, false>(t * 64, (t + 1) * 64, K0, V0, K1, V1, kgb, vgb,
                           tid, lg, lm, kvbase, qf16, m_, l_, oacc, pexw, N);
    asm volatile("s_waitcnt vmcnt(0)" ::: "memory");
    __builtin_amdgcn_s_barrier();
    attn_tile<true, false>((t + 1) * 64, (t + 2) * 64, K1, V1, K0, V0, kgb, vgb,
                           tid, lg, lm, kvbase, qf16, m_, l_, oacc, pexw, N);
    asm volatile("s_waitcnt vmcnt(0)" ::: "memory");
    __builtin_amdgcn_s_barrier();
  }
  attn_tile<false, true>(32 * 64, 0, K0, V0, K1, V1, kgb, vgb,
                         tid, lg, lm, kvbase, qf16, m_, l_, oacc, pexw, N);

  // epilogue: O/l -> f16 hi/lo (feeds final f16x2 GEMM)
#pragma unroll
  for (int qf = 0; qf < 2; ++qf) {
    int t = qbase + qf * 16 + lm;
    if (t < N) {
      float rl = 1.f / l_[qf];
      size_t rowoff = ((size_t)(b * N + t)) * 1024 + h * 64 + lg * 4;
#pragma unroll
      for (int c = 0; c < 4; ++c) {
        float v0 = oacc[qf][c][0] * rl, v1 = oacc[qf][c][1] * rl;
        float v2 = oacc[qf][c][2] * rl, v3 = oacc[qf][c][3] * rl;
        u16 h0 = f2h(v0), h1 = f2h(v1), h2 = f2h(v2), h3 = f2h(v3);
        unsigned hh01 = (unsigned)h0 | ((unsigned)h1 << 16);
        unsigned hh23 = (unsigned)h2 | ((unsigned)h3 << 16);
        unsigned ll01 = pk_h(v0 - h2f(h0), v1 - h2f(h1));
        unsigned ll23 = pk_h(v2 - h2f(h2), v3 - h2f(h3));
        *(uint2*)(outh + rowoff + c * 16) = make_uint2(hh01, hh23);
        *(uint2*)(outl + rowoff + c * 16) = make_uint2(ll01, ll23);
      }
    }
  }
}

// ---------------- orchestration ----------------
extern "C" void kernel_launch(void* const* d_in, const int* in_sizes, int n_in,
                              void* d_out, int out_size, void* d_ws, size_t ws_size,
                              hipStream_t stream) {
  const float* x     = (const float*)d_in[0];
  const int*   pos   = (const int*)  d_in[1];
  const float* w_qkv = (const float*)d_in[2];
  const float* b_qkv = (const float*)d_in[3];
  const float* w_fc  = (const float*)d_in[4];
  const float* b_fc  = (const float*)d_in[5];
  (void)in_sizes; (void)n_in; (void)out_size; (void)ws_size;

  const int B = 4, N = 2049, NP = 2112;  // NP = 33*64 (KVBLK=64 tiles)
  const long EL = (long)B * N * 1024;       // 8,392,704
  const long ELP = (long)B * 16 * NP * 64;  // padded K elems

  char* base = (char*)d_ws;
  size_t off = 0;
  auto alloc = [&](size_t bytes) -> void* {
    void* p = base + off;
    off += (bytes + 255) & ~(size_t)255;
    return p;
  };
  u16* qhh = (u16*)alloc(EL * 2);                      // q f16 (scaled)
  u16* khh = (u16*)alloc(ELP * 2);                     // k f16 (padded rows)
  u16* vbh = (u16*)alloc(EL * 2);                      // v f16 row-major
  u16* vth = (u16*)alloc((size_t)64 * 64 * NP * 2);    // v^T f16 padded cols
  u16* xh  = (u16*)alloc(EL * 2);                      // x / attn-out f16 hi
  u16* xl  = (u16*)alloc(EL * 2);                      // x / attn-out f16 lo
  u16* wq  = (u16*)alloc((size_t)3072 * 1024 * 2);     // w_qkv f16
  u16* wf  = (u16*)alloc((size_t)1024 * 1024 * 2);     // w_fc f16
  float2* cst = (float2*)alloc((size_t)B * 2048 * 32 * 8);

  // 1. split x to f16 hi/lo; cast weights to f16; build cos/sin table
  splitf16_kernel<<<2048, 256, 0, stream>>>(x, xh, xl, EL / 4);
  castf16_kernel<<<1024, 256, 0, stream>>>(w_qkv, wq, (long)3072 * 1024 / 4);
  castf16_kernel<<<256, 256, 0, stream>>>(w_fc, wf, (long)1024 * 1024 / 4);
  cs_table_kernel<<<(B * 2048 * 32) / 256, 256, 0, stream>>>(pos, cst);
  // 2. fused QKV projection (f16x2 A, f16 W) with fused RoPE + f16 q/k/v epilogue
  gemm_f16x2<0><<<dim3(24 * 65), 256, 0, stream>>>(xh, xl, wq, b_qkv, cst, nullptr,
                                                   qhh, khh, vbh, 8196, 3072, 1024, N, NP);
  // 3. pad K rows [N,NP); transpose+pad V (f16 -> [bh][64][NP])
  kpad_kernel<<<(64 * (NP - N) * 32 + 255) / 256, 256, 0, stream>>>(khh, N, NP);
  vtransT_kernel<<<dim3(NP / 64, 64), 256, 0, stream>>>(vbh, vth, N, NP);
  // 4. flash attention (f16 core, 8-wave/256-row blocks) -> f16 hi/lo, reusing xh/xl
  attn_kernel<<<dim3(576), 512, 0, stream>>>(qhh, khh, vth, xh, xl, N, NP);
  // 5. output projection -> d_out
  gemm_f16x2<1><<<dim3(8 * 65), 256, 0, stream>>>(xh, xl, wf, b_fc, nullptr,
                                                  (float*)d_out, nullptr, nullptr, nullptr,
                                                  8196, 1024, 1024, N, NP);
}